// Round 1
// 412.083 us; speedup vs baseline: 1.0167x; 1.0167x over previous
//
#include <hip/hip_runtime.h>
#include <hip/hip_bf16.h>
#include <math.h>

#define E_EDGES 131072
#define NN1 8192
#define NN2 6560          // 16*410
#define NG 16
#define NP1 512
#define KP1 410
#define KP2 205
#define F1 1536
#define EMB 512
#define MAXDEG 256
#define BNCH 256          // (legacy sizing constant for ws layout)

typedef __hip_bfloat16 bf16;
typedef __attribute__((ext_vector_type(8))) short short8;
typedef __attribute__((ext_vector_type(4))) float f32x4;
typedef __attribute__((ext_vector_type(4))) unsigned short us4;

__device__ inline float wred64(float v){
  #pragma unroll
  for (int o = 32; o; o >>= 1) v += __shfl_down(v, o);
  return v;
}
__device__ inline float b2f_raw(unsigned short u){
  return __uint_as_float((unsigned)u << 16);
}
union BFU { bf16 b; unsigned short u; };
__device__ inline unsigned short f2u(float v){ BFU x; x.b = __float2bfloat16(v); return x.u; }

__device__ __forceinline__ void gld16(const void* g, void* l){
  __builtin_amdgcn_global_load_lds(
      (const __attribute__((address_space(1))) void*)g,
      (__attribute__((address_space(3))) void*)l, 16, 0, 0);
}

__device__ inline void split_store(float v, bf16* __restrict__ ph, bf16* __restrict__ pl){
  bf16 hi = __float2bfloat16(v);
  *ph = hi;
  *pl = __float2bfloat16(v - __bfloat162float(hi));
}

// shared tail: write mean/inv-sigma + pnorm
__device__ inline void bn_tail(float s, float q, int c, float* __restrict__ stats,
    int M, const float* __restrict__ p, float* __restrict__ pnout){
  float mean = s / (float)M;
  float var = fmaxf(q / (float)M - mean*mean, 0.f);
  stats[c] = mean;
  stats[512+c] = 1.f / sqrtf(var + 1e-5f);
  float v = p[c]; v = v*v;
  v = wred64(v);
  __shared__ float red[8];
  int lane = c & 63, wv = c >> 6;
  if (lane == 0) red[wv] = v;
  __syncthreads();
  if (c == 0){ float sm = 0.f; for (int i = 0; i < 8; i++) sm += red[i]; pnout[0] = sqrtf(sm); }
}

// ======================= fused per-launch precompute =======================
// blocks [0,18): M1 full-K   [18,22): cvec full-K   [22,34): watt2
// [34,52): watt1             [52,84): init (cnt/map/bnacc)
__global__ __launch_bounds__(256) void k_pre(
    const float* __restrict__ W1, const float* __restrict__ as1, const float* __restrict__ ad1,
    const float* __restrict__ Wh1, const float* __restrict__ bc1, const float* __restrict__ bh1,
    const float* __restrict__ W2, const float* __restrict__ as2, const float* __restrict__ ad2,
    const float* __restrict__ Wh2, const float* __restrict__ bc2, const float* __restrict__ bh2,
    float* __restrict__ was1, float* __restrict__ wad1, float* __restrict__ M1,
    float* __restrict__ cvec1, float* __restrict__ cvec2,
    float* __restrict__ was2, float* __restrict__ wad2,
    int* __restrict__ cnt1, int* __restrict__ cnt2, int* __restrict__ map,
    float* __restrict__ bnacc, float* __restrict__ bnacc1){
  int b = blockIdx.x, t = threadIdx.x;
  if (b < 18){                               // M1[r*512+j], full K=512, no atomics
    int r = b >> 1, bx = b & 1;
    int h = r / 3, f = r % 3;
    int j = bx*256 + t;
    const float* wrow = W1 + f*1536 + h*512;
    const float* whc  = Wh1 + (size_t)(h*512)*512 + j;
    float a0=0,a1=0,a2=0,a3=0;
    #pragma unroll 4
    for (int c = 0; c < 512; c += 4){
      a0 += wrow[c]   * whc[(size_t)c*512];
      a1 += wrow[c+1] * whc[(size_t)(c+1)*512];
      a2 += wrow[c+2] * whc[(size_t)(c+2)*512];
      a3 += wrow[c+3] * whc[(size_t)(c+3)*512];
    }
    M1[r*512 + j] = (a0+a1)+(a2+a3);
  } else if (b < 22){                        // cvec = bh + bc @ Wh, full K=1536
    int bb = b - 18; int which = bb >> 1, bx = bb & 1;
    const float* bc = which ? bc2 : bc1;
    const float* Wh = which ? Wh2 : Wh1;
    const float* bh = which ? bh2 : bh1;
    float* cv       = which ? cvec2 : cvec1;
    int j = bx*256 + t;
    float a0=0,a1=0,a2=0,a3=0;
    #pragma unroll 4
    for (int i = 0; i < 1536; i += 4){
      a0 += bc[i]   * Wh[(size_t)i*512 + j];
      a1 += bc[i+1] * Wh[(size_t)(i+1)*512 + j];
      a2 += bc[i+2] * Wh[(size_t)(i+2)*512 + j];
      a3 += bc[i+3] * Wh[(size_t)(i+3)*512 + j];
    }
    cv[j] = bh[j] + (a0+a1)+(a2+a3);
  } else if (b < 34){                        // watt2
    int y = (b - 22) >> 1, bx = (b - 22) & 1;
    int e = bx*256 + t;
    int kind = y / 3, h = y % 3;
    const float* att = kind ? ad2 : as2;
    const float4* row = (const float4*)(W2 + (size_t)e*1536 + h*512);
    const float4* av  = (const float4*)(att + h*512);
    float acc = 0.f;
    #pragma unroll 4
    for (int c4 = 0; c4 < 128; c4++){
      float4 wv = row[c4], a = av[c4];
      acc += wv.x*a.x + wv.y*a.y + wv.z*a.z + wv.w*a.w;
    }
    (kind ? wad2 : was2)[h*512 + e] = acc;
  } else if (b < 52){                        // watt1 (1 wave active)
    if (t < 64){
      int bb = b - 34;
      int kind = bb / 9, r = bb % 9, h = r / 3, f = r % 3;
      const float* att = kind ? ad1 : as1;
      float s = 0.f;
      for (int c = t; c < 512; c += 64) s += W1[f*1536 + h*512 + c] * att[h*512 + c];
      s = wred64(s);
      if (t == 0) (kind ? wad1 : was1)[h*3 + f] = s;
    }
  } else {                                   // init
    int i = (b - 52)*256 + t;
    if (i < NN1){ cnt1[i] = 1; map[i] = -1; }
    if (i < NN2){ cnt2[i] = 1; }
    if (i < 1024){ bnacc[i] = 0.f; bnacc1[i] = 0.f; }
  }
}

// ======================= M2 precompute: bf16 3-pass split MFMA GEMM =======================
// C_z[m][n] = sum_k W2[m, z*512+k] * Wh2[z*512+k, n];  64x64 tile, BK=64, 256 thr (4 waves)
// A,B split into (hi,lo) bf16 in LDS; acc = AhBh + AhBl + AlBh (AlBl ~2^-18, dropped).
// Output: transposed split store Th/Tl[(n)*1536 + z*512 + m].
__global__ __launch_bounds__(256) void k_gemm_s_mfma(const float* __restrict__ A0,
    const float* __restrict__ B0, bf16* __restrict__ Th, bf16* __restrict__ Tl){
  int z = blockIdx.z;
  const float* A = A0 + (size_t)z*512;            // row stride 1536 (k-contig)
  const float* B = B0 + (size_t)z*512*512;        // row stride 512 (n-contig)
  __shared__ __align__(16) short sAh[4096], sAl[4096], sBh[4096], sBl[4096];
  int t = threadIdx.x, w = t >> 6, lane = t & 63;
  int l16 = lane & 15, q = lane >> 4;
  int bm = blockIdx.y*64, bn = blockIdx.x*64;

  // staging maps
  int am  = t >> 2, akw = (t & 3)*16;             // A: row am, k window akw..akw+15
  int bnl = t & 63, bkq = (t >> 6)*16;            // B: col bnl, k window bkq..bkq+15

  f32x4 acc[4];
  #pragma unroll
  for (int nf = 0; nf < 4; nf++) acc[nf] = (f32x4){0.f,0.f,0.f,0.f};

  float va[16], vb[16];
  #define GS_LOAD(K0) do { \
    _Pragma("unroll") for (int u = 0; u < 4; u++){ \
      float4 v4 = *(const float4*)(A + (size_t)(bm+am)*1536 + (K0) + akw + u*4); \
      va[u*4]=v4.x; va[u*4+1]=v4.y; va[u*4+2]=v4.z; va[u*4+3]=v4.w; } \
    _Pragma("unroll") for (int u = 0; u < 16; u++) \
      vb[u] = B[(size_t)((K0) + bkq + u)*512 + bn + bnl]; \
  } while(0)

  GS_LOAD(0);
  for (int it = 0; it < 8; it++){
    // convert+split+swizzled LDS write
    #pragma unroll
    for (int hh = 0; hh < 2; hh++){
      short8 ah_, al_, bh_, bl_;
      #pragma unroll
      for (int jj = 0; jj < 8; jj++){
        float v = va[hh*8+jj];
        unsigned short hu = f2u(v);
        ah_[jj] = (short)hu; al_[jj] = (short)f2u(v - b2f_raw(hu));
        v = vb[hh*8+jj];
        hu = f2u(v);
        bh_[jj] = (short)hu; bl_[jj] = (short)f2u(v - b2f_raw(hu));
      }
      int aoff = am*64  + ((((akw>>3) + hh) ^ (am  & 7)) << 3);
      *(short8*)(sAh + aoff) = ah_;
      *(short8*)(sAl + aoff) = al_;
      int boff = bnl*64 + ((((bkq>>3) + hh) ^ (bnl & 7)) << 3);
      *(short8*)(sBh + boff) = bh_;
      *(short8*)(sBl + boff) = bl_;
    }
    __syncthreads();
    if (it < 7) GS_LOAD((it+1)*64);              // prefetch overlaps MFMA below
    #pragma unroll
    for (int ks = 0; ks < 2; ks++){
      int gc = ks*4 + q;
      int ar = w*16 + l16;
      int ao = ar*64 + ((gc ^ (ar & 7)) << 3);
      short8 afh = *(const short8*)(sAh + ao);
      short8 afl = *(const short8*)(sAl + ao);
      #pragma unroll
      for (int nf = 0; nf < 4; nf++){
        int br = nf*16 + l16;
        int bo = br*64 + ((gc ^ (br & 7)) << 3);
        short8 bfh = *(const short8*)(sBh + bo);
        short8 bfl = *(const short8*)(sBl + bo);
        acc[nf] = __builtin_amdgcn_mfma_f32_16x16x32_bf16(afh, bfh, acc[nf], 0, 0, 0);
        acc[nf] = __builtin_amdgcn_mfma_f32_16x16x32_bf16(afh, bfl, acc[nf], 0, 0, 0);
        acc[nf] = __builtin_amdgcn_mfma_f32_16x16x32_bf16(afl, bfh, acc[nf], 0, 0, 0);
      }
    }
    __syncthreads();
  }
  #undef GS_LOAD

  // epilogue: D row = q*4+e (m), col = l16 (n); store transposed + split
  int m0 = bm + w*16 + q*4;
  #pragma unroll
  for (int nf = 0; nf < 4; nf++){
    int n = bn + nf*16 + l16;
    size_t base = (size_t)n*1536 + (size_t)z*512 + m0;
    #pragma unroll
    for (int e = 0; e < 4; e++)
      split_store(acc[nf][e], &Th[base+e], &Tl[base+e]);
  }
}

// ======================= CSR build =======================
__global__ void k_count1(const int* __restrict__ tgt0, int* __restrict__ cnt, int E){
  int i = blockIdx.x*blockDim.x + threadIdx.x;
  if (i < E) atomicAdd(&cnt[tgt0[i]], 1);
}
__global__ void k_count2(const int* __restrict__ src0, const int* __restrict__ tgt0,
                         const int* __restrict__ map, int* __restrict__ cnt, int E){
  int i = blockIdx.x*blockDim.x + threadIdx.x;
  if (i >= E) return;
  int s = map[src0[i]], tg = map[tgt0[i]];
  if (s >= 0 && tg >= 0) atomicAdd(&cnt[tg], 1);
}
__global__ __launch_bounds__(1024) void k_scan(const int* __restrict__ counts,
    int* __restrict__ off, int* __restrict__ cur, int n){
  __shared__ int sh[1024];
  int t = threadIdx.x;
  int chunk = (n + 1023) >> 10;
  int b = t * chunk; int e = b + chunk; if (e > n) e = n;
  int s = 0;
  for (int i = b; i < e && i < n; i++) s += counts[i];
  sh[t] = s; __syncthreads();
  for (int o = 1; o < 1024; o <<= 1){
    int v = (t >= o) ? sh[t-o] : 0;
    __syncthreads();
    sh[t] += v;
    __syncthreads();
  }
  int run = (t > 0) ? sh[t-1] : 0;
  for (int i = b; i < e && i < n; i++){ int c = counts[i]; off[i] = run; cur[i] = run; run += c; }
  if (t == 1023) off[n] = sh[1023];
}
__global__ void k_fill1(const int* __restrict__ src0, const int* __restrict__ tgt0,
                        int* __restrict__ cur, int* __restrict__ esrc, int E, int nn){
  int i = blockIdx.x*blockDim.x + threadIdx.x;
  if (i >= E + nn) return;
  int s, tg;
  if (i < E){ s = src0[i]; tg = tgt0[i]; } else { s = i - E; tg = s; }
  int pos = atomicAdd(&cur[tg], 1);
  esrc[pos] = s;
}
__global__ void k_fill2(const int* __restrict__ src0, const int* __restrict__ tgt0,
                        const int* __restrict__ map, int* __restrict__ cur,
                        int* __restrict__ esrc, int E, int nn){
  int i = blockIdx.x*blockDim.x + threadIdx.x;
  if (i >= E + nn) return;
  int s, tg;
  if (i < E){
    s = map[src0[i]]; tg = map[tgt0[i]];
    if (s < 0 || tg < 0) return;
  } else { s = i - E; tg = s; }
  int pos = atomicAdd(&cur[tg], 1);
  esrc[pos] = s;
}

// ======================= layer 1: aggregate raw x (3 features) =======================
__global__ __launch_bounds__(64) void k_agg1(
    const float* __restrict__ x, const int* __restrict__ off, const int* __restrict__ esrc,
    const float* __restrict__ was, const float* __restrict__ wad,
    float* __restrict__ aggx){          // [n*9], idx h*3+f
  int n = blockIdx.x, t = threadIdx.x;  // 64 threads = 1 wave
  __shared__ float xs[MAXDEG][3];
  __shared__ float al[MAXDEG*3];
  __shared__ float mh[3], dh[3];
  int s0 = off[n]; int deg = off[n+1] - s0; if (deg > MAXDEG) deg = MAXDEG;
  float ad0, ad1, ad2;
  {
    float x0 = x[n*3], x1 = x[n*3+1], x2 = x[n*3+2];
    ad0 = x0*wad[0] + x1*wad[1] + x2*wad[2];
    ad1 = x0*wad[3] + x1*wad[4] + x2*wad[5];
    ad2 = x0*wad[6] + x1*wad[7] + x2*wad[8];
  }
  for (int e = t; e < deg; e += 64){
    int s = esrc[s0 + e];
    float x0 = x[s*3], x1 = x[s*3+1], x2 = x[s*3+2];
    xs[e][0] = x0; xs[e][1] = x1; xs[e][2] = x2;
    float v0 = x0*was[0] + x1*was[1] + x2*was[2] + ad0;
    float v1 = x0*was[3] + x1*was[4] + x2*was[5] + ad1;
    float v2 = x0*was[6] + x1*was[7] + x2*was[8] + ad2;
    al[e*3+0] = v0 > 0.f ? v0 : 0.2f*v0;
    al[e*3+1] = v1 > 0.f ? v1 : 0.2f*v1;
    al[e*3+2] = v2 > 0.f ? v2 : 0.2f*v2;
  }
  __syncthreads();
  if (t < 3){
    float m = -INFINITY;
    for (int e = 0; e < deg; e++) m = fmaxf(m, al[e*3+t]);
    float d = 0.f;
    for (int e = 0; e < deg; e++) d += expf(al[e*3+t] - m);
    mh[t] = m; dh[t] = 1.f / fmaxf(d, 1e-16f);
  }
  __syncthreads();
  float acc[9] = {0,0,0,0,0,0,0,0,0};
  for (int e = t; e < deg; e += 64){
    #pragma unroll
    for (int h = 0; h < 3; h++){
      float a = expf(al[e*3+h] - mh[h]) * dh[h];
      acc[h*3+0] += a * xs[e][0];
      acc[h*3+1] += a * xs[e][1];
      acc[h*3+2] += a * xs[e][2];
    }
  }
  #pragma unroll
  for (int q = 0; q < 9; q++){
    float v = wred64(acc[q]);
    if (t == 0) aggx[(size_t)n*9 + q] = v;
  }
}

// h1[n,j] = relu(cvec[j] + sum_q aggx[n,q]*M1[q,j]) -> bf16 ; 32 nodes/block, fused BN partials
__global__ __launch_bounds__(256) void k_h1(const float* __restrict__ aggx,
    const float* __restrict__ M1, const float* __restrict__ cvec, bf16* __restrict__ hout,
    float* __restrict__ bnacc1){
  __shared__ float sM[9*512];
  __shared__ float sC[512];
  __shared__ float sA[32*9];
  int t = threadIdx.x; int n0 = blockIdx.x*32;
  for (int i = t; i < 9*512; i += 256) sM[i] = M1[i];
  for (int i = t; i < 512; i += 256) sC[i] = cvec[i];
  for (int i = t; i < 288; i += 256) sA[i] = aggx[(size_t)n0*9 + i];
  __syncthreads();
  float c0v = sC[t], c1v = sC[t+256];
  float ls0=0.f, lq0=0.f, ls1=0.f, lq1=0.f;
  #pragma unroll 4
  for (int i = 0; i < 32; i++){
    float a0 = c0v, a1 = c1v;
    #pragma unroll
    for (int q = 0; q < 9; q++){
      float av = sA[i*9+q];
      a0 += av * sM[q*512 + t];
      a1 += av * sM[q*512 + t + 256];
    }
    a0 = fmaxf(a0, 0.f); a1 = fmaxf(a1, 0.f);
    hout[(size_t)(n0+i)*512 + t]       = __float2bfloat16(a0);
    hout[(size_t)(n0+i)*512 + t + 256] = __float2bfloat16(a1);
    ls0 += a0; lq0 += a0*a0; ls1 += a1; lq1 += a1*a1;
  }
  atomicAdd(&bnacc1[t],           ls0);
  atomicAdd(&bnacc1[t+256],       ls1);
  atomicAdd(&bnacc1[512 + t],     lq0);
  atomicAdd(&bnacc1[512 + t+256], lq1);
}

// ======================= BN / score =======================
// totals already in acc[0..511]=sum, [512..1023]=sq
__global__ void k_bn_final_1(const float* __restrict__ bnacc,
    float* __restrict__ stats, int M, const float* __restrict__ p, float* __restrict__ pnout){
  int c = threadIdx.x;
  bn_tail(bnacc[c], bnacc[512 + c], c, stats, M, p, pnout);
}
// score only (y not materialized), bf16 h
__global__ __launch_bounds__(256) void k_score(
    const bf16* __restrict__ h, const float* __restrict__ stats,
    const float* __restrict__ g_, const float* __restrict__ be,
    const float* __restrict__ p, const float* __restrict__ pn,
    float* __restrict__ score){
  int r = blockIdx.x, t = threadIdx.x;
  float dot = 0.f;
  #pragma unroll
  for (int k = 0; k < 2; k++){
    int c = t + k*256;
    float v = (__bfloat162float(h[(size_t)r*EMB + c]) - stats[c]) * stats[512+c] * g_[c] + be[c];
    dot += v * p[c];
  }
  dot = wred64(dot);
  __shared__ float red[4];
  int lane = t & 63, wv = t >> 6;
  if (lane == 0) red[wv] = dot;
  __syncthreads();
  if (t == 0) score[r] = tanhf((red[0]+red[1]+red[2]+red[3]) / pn[0]);
}

// ======================= top-k =======================
__global__ __launch_bounds__(512) void k_topk_sort(
    const float* __restrict__ score, int* __restrict__ map,
    int* __restrict__ topi, float* __restrict__ tops, int n_per, int K){
  int g = blockIdx.x, t = threadIdx.x;     // 512 threads, 1 elem each
  __shared__ float sk[512];
  __shared__ int si[512];
  if (t < n_per){ sk[t] = score[g*n_per + t]; si[t] = t; }
  else { sk[t] = -INFINITY; si[t] = 0x7fffffff; }
  __syncthreads();
  for (int k = 2; k <= 512; k <<= 1){
    for (int j = k >> 1; j > 0; j >>= 1){
      int l = t ^ j;
      if (l > t){
        float ki = sk[t], kl = sk[l]; int ii = si[t], il = si[l];
        bool before_l = (kl > ki) || (kl == ki && il < ii);
        bool up = ((t & k) == 0);
        if (up == before_l){ sk[t]=kl; sk[l]=ki; si[t]=il; si[l]=ii; }
      }
      __syncthreads();
    }
  }
  if (t < K){
    if (map) map[g*n_per + si[t]] = g*K + t;
    topi[g*K + t] = si[t];
    tops[g*K + t] = sk[t];
  }
}

// gather + on-the-fly BN + scale -> bf16; fused layer-2 attention dots (layer-1 only now)
__global__ __launch_bounds__(256) void k_topk_gather(
    const bf16* __restrict__ h, const float* __restrict__ stats,
    const float* __restrict__ gm, const float* __restrict__ be,
    const int* __restrict__ topi, const float* __restrict__ tops,
    bf16* __restrict__ xn, int n_per, int K,
    const float* __restrict__ was2, const float* __restrict__ wad2,
    float* __restrict__ aso, float* __restrict__ ado){
  int row = blockIdx.x, t = threadIdx.x;
  int gr = row / K, i = row - gr*K;
  int sidx = topi[gr*K + i];
  float s = tops[gr*K + i];
  const bf16* src = h + ((size_t)(gr*n_per + sidx))*EMB;
  bf16* dst = xn + (size_t)row*EMB;
  int c0 = t, c1 = t + 256;
  float v0 = ((__bfloat162float(src[c0]) - stats[c0]) * stats[512+c0] * gm[c0] + be[c0]) * s;
  float v1 = ((__bfloat162float(src[c1]) - stats[c1]) * stats[512+c1] * gm[c1] + be[c1]) * s;
  dst[c0] = __float2bfloat16(v0);
  dst[c1] = __float2bfloat16(v1);
  if (was2){
    float a[6];
    #pragma unroll
    for (int hh = 0; hh < 3; hh++){
      a[hh]   = v0*was2[hh*512 + c0] + v1*was2[hh*512 + c1];
      a[3+hh] = v0*wad2[hh*512 + c0] + v1*wad2[hh*512 + c1];
    }
    __shared__ float red[6][4];
    int lane = t & 63, wv = t >> 6;
    #pragma unroll
    for (int q = 0; q < 6; q++){ float v = wred64(a[q]); if (lane==0) red[q][wv]=v; }
    __syncthreads();
    if (t < 6){
      float sm = red[t][0]+red[t][1]+red[t][2]+red[t][3];
      if (t < 3) aso[row*3+t] = sm; else ado[row*3+(t-3)] = sm;
    }
  }
}

// ======================= pooling =======================
// layer-1: single-kernel max+mean over xn1 (bf16)
__global__ __launch_bounds__(512) void k_poolA(const bf16* __restrict__ xn,
    float* __restrict__ cat, int K){
  int g = blockIdx.x, c = threadIdx.x;
  const unsigned short* p = (const unsigned short*)xn + (size_t)g*K*EMB + c;
  float mx = -INFINITY, sm = 0.f;
  #pragma unroll 4
  for (int r = 0; r < K; r++){
    float v = b2f_raw(p[(size_t)r*EMB]);
    mx = fmaxf(mx, v); sm += v;
  }
  cat[g*1024 + c] = mx;
  cat[g*1024 + 512 + c] = sm / (float)K;
}
// layer-2: fused gather + BN + scale + max/mean pool directly from Cc (no xn2)
__global__ __launch_bounds__(512) void k_poolB(const bf16* __restrict__ h,
    const float* __restrict__ stats, const float* __restrict__ gm, const float* __restrict__ be,
    const int* __restrict__ topi, const float* __restrict__ tops,
    float* __restrict__ cat, int n_per, int K){
  int g = blockIdx.x, c = threadIdx.x;
  __shared__ int sti[256];
  __shared__ float sts[256];
  for (int r = c; r < K; r += 512){ sti[r] = topi[g*K + r]; sts[r] = tops[g*K + r]; }
  __syncthreads();
  float mean = stats[c], inv = stats[512+c];
  float gg = gm[c], bb = be[c];
  const unsigned short* hp = (const unsigned short*)h;
  float mx = -INFINITY, sm = 0.f;
  #pragma unroll 4
  for (int r = 0; r < K; r++){
    float v = (b2f_raw(hp[(size_t)(g*n_per + sti[r])*EMB + c]) - mean) * inv * gg + bb;
    v *= sts[r];
    mx = fmaxf(mx, v); sm += v;
  }
  cat[g*1024 + c] = mx;
  cat[g*1024 + 512 + c] = sm / (float)K;
}

// ======================= layer 2 aggregation (bf16 xn input) =======================
__global__ __launch_bounds__(256) void k_agg2(
    const bf16* __restrict__ xn, const float* __restrict__ aso, const float* __restrict__ ado,
    const int* __restrict__ off, const int* __restrict__ esrc,
    bf16* __restrict__ oh){
  int n = blockIdx.x, t = threadIdx.x;
  __shared__ int srcs[MAXDEG];
  __shared__ float al[MAXDEG*3];
  __shared__ float mh[3], dh[3];
  int s0 = off[n]; int deg = off[n+1] - s0; if (deg > MAXDEG) deg = MAXDEG;
  for (int e = t; e < deg; e += 256) srcs[e] = esrc[s0 + e];
  __syncthreads();
  float ad0 = ado[n*3+0], ad1 = ado[n*3+1], ad2 = ado[n*3+2];
  for (int e = t; e < deg; e += 256){
    int s = srcs[e];
    float v0 = aso[s*3+0] + ad0, v1 = aso[s*3+1] + ad1, v2 = aso[s*3+2] + ad2;
    al[e*3+0] = v0 > 0.f ? v0 : 0.2f*v0;
    al[e*3+1] = v1 > 0.f ? v1 : 0.2f*v1;
    al[e*3+2] = v2 > 0.f ? v2 : 0.2f*v2;
  }
  __syncthreads();
  if (t < 3){
    float m = -INFINITY;
    for (int e = 0; e < deg; e++) m = fmaxf(m, al[e*3+t]);
    float d = 0.f;
    for (int e = 0; e < deg; e++) d += expf(al[e*3+t] - m);
    mh[t] = m; dh[t] = 1.f / fmaxf(d, 1e-16f);
  }
  __syncthreads();
  for (int e = t; e < deg; e += 256){
    al[e*3+0] = expf(al[e*3+0]-mh[0])*dh[0];
    al[e*3+1] = expf(al[e*3+1]-mh[1])*dh[1];
    al[e*3+2] = expf(al[e*3+2]-mh[2])*dh[2];
  }
  __syncthreads();
  float acc[2][3] = {};
  for (int e = 0; e < deg; e++){
    int s = srcs[e];
    float a0 = al[e*3], a1 = al[e*3+1], a2 = al[e*3+2];
    #pragma unroll
    for (int k = 0; k < 2; k++){
      float v = __bfloat162float(xn[(size_t)s*512 + t + k*256]);
      acc[k][0] += a0*v; acc[k][1] += a1*v; acc[k][2] += a2*v;
    }
  }
  #pragma unroll
  for (int k = 0; k < 2; k++){
    int c = t + k*256;
    #pragma unroll
    for (int h = 0; h < 3; h++)
      oh[(size_t)n*1536 + h*512 + c] = __float2bfloat16(acc[k][h]);
  }
}

// ======================= bf16-A x split-bf16-B MFMA GEMM =======================
// 128x64 tile, BK=64, XOR-swizzled LDS, double-buffered prefetch-after-barrier.
// bf16 C output + fused BN partial stats (atomicAdd into bnacc[0..511]=sum, [512..1023]=sq).
__global__ __launch_bounds__(256, 2) void k_gemm_mfma(
    const bf16* __restrict__ Ah,
    const bf16* __restrict__ Bh, const bf16* __restrict__ Bl,   // [N][K] row-major
    const float* __restrict__ bias, bf16* __restrict__ C,
    float* __restrict__ bnacc,
    int M, int N, int K, int Mtiles){
  __shared__ __align__(16) unsigned short lds[2][16384];   // 64 KB total
  int t = threadIdx.x, w = t >> 6, lane = t & 63;
  int q = lane >> 4, l16 = lane & 15;
  int bmi = (int)blockIdx.x % Mtiles, bni = (int)blockIdx.x / Mtiles;
  int bm = bmi * 128, bn = bni * 64;

  int lr = lane >> 3, lc = lane & 7;
  int kg = ((lc ^ lr) & 7) * 8;          // swizzled global k element offset
  int ro = w*8 + lr;
  int m0 = bm + ro, m1 = bm + 32 + ro, m2 = bm + 64 + ro, m3 = bm + 96 + ro;
  if (m0 >= M) m0 = M-1;  if (m1 >= M) m1 = M-1;
  if (m2 >= M) m2 = M-1;  if (m3 >= M) m3 = M-1;
  int n0 = bn + ro, n1 = bn + 32 + ro;
  const bf16* ptr[8];
  ptr[0] = Ah + (size_t)m0*K + kg;
  ptr[1] = Ah + (size_t)m1*K + kg;
  ptr[2] = Ah + (size_t)m2*K + kg;
  ptr[3] = Ah + (size_t)m3*K + kg;
  ptr[4] = Bh + (size_t)n0*K + kg;
  ptr[5] = Bh + (size_t)n1*K + kg;
  ptr[6] = Bl + (size_t)n0*K + kg;
  ptr[7] = Bl + (size_t)n1*K + kg;
  const int dof[8] = {0, 2048, 4096, 6144, 8192, 10240, 12288, 14336};

  int wm = (w >> 1) * 64, wn = (w & 1) * 32;
  f32x4 acc[4][2];
  #pragma unroll
  for (int i = 0; i < 4; i++)
    #pragma unroll
    for (int j = 0; j < 2; j++)
      acc[i][j] = (f32x4){0.f, 0.f, 0.f, 0.f};

  #pragma unroll
  for (int u = 0; u < 8; u++){
    gld16(ptr[u], &lds[0][dof[u] + w*512]);
    ptr[u] += 64;
  }

  int nit = K >> 6;
  for (int it = 0; it < nit; it++){
    __syncthreads();
    int cur = it & 1;
    if (it + 1 < nit){
      int nxt = cur ^ 1;
      #pragma unroll
      for (int u = 0; u < 8; u++){
        gld16(ptr[u], &lds[nxt][dof[u] + w*512]);
        ptr[u] += 64;
      }
    }
    const unsigned short* L = lds[cur];
    #pragma unroll
    for (int ks = 0; ks < 2; ks++){
      short8 ah[4], bh2[2], bl2[2];
      int gc = ks*4 + q;
      #pragma unroll
      for (int i = 0; i < 4; i++){
        int r = wm + i*16 + l16;
        ah[i] = *(const short8*)(L + r*64 + ((gc ^ (r & 7)) << 3));
      }
      #pragma unroll
      for (int j = 0; j < 2; j++){
        int r = wn + j*16 + l16;
        int so = ((gc ^ (r & 7)) << 3);
        bh2[j] = *(const short8*)(L + 8192  + r*64 + so);
        bl2[j] = *(const short8*)(L + 12288 + r*64 + so);
      }
      #pragma unroll
      for (int i = 0; i < 4; i++)
        #pragma unroll
        for (int j = 0; j < 2; j++){
          acc[i][j] = __builtin_amdgcn_mfma_f32_16x16x32_bf16(ah[i], bh2[j], acc[i][j], 0, 0, 0);
          acc[i][j] = __builtin_amdgcn_mfma_f32_16x16x32_bf16(ah[i], bl2[j], acc[i][j], 0, 0, 0);
        }
    }
  }

  // epilogue: relu + bf16 store + per-column BN partials
  __syncthreads();                       // LDS now free for reduction scratch
  float* cs = (float*)&lds[0][0];        // [2][64] col sums | [2][64] col sqs
  float* cq = cs + 128;
  int slot = w >> 1;
  #pragma unroll
  for (int j = 0; j < 2; j++){
    int c_local = wn + j*16 + l16;
    int c = bn + c_local;
    float bv = bias ? bias[c] : 0.f;
    float ls = 0.f, lq = 0.f;
    #pragma unroll
    for (int i = 0; i < 4; i++){
      int rb = bm + wm + i*16 + q*4;
      #pragma unroll
      for (int e = 0; e < 4; e++){
        int r = rb + e;
        if (r < M){
          float v = fmaxf(acc[i][j][e] + bv, 0.f);
          C[(size_t)r*N + c] = __float2bfloat16(v);
          ls += v; lq += v*v;
        }
      }
    }
    ls += __shfl_xor(ls, 16); ls += __shfl_xor(ls, 32);
    lq += __shfl_xor(lq, 16); lq += __shfl_xor(lq, 32);
    if (q == 0){ cs[slot*64 + c_local] = ls; cq[slot*64 + c_local] = lq; }
  }
  __syncthreads();
  if (t < 64){
    atomicAdd(&bnacc[bn + t],        cs[t] + cs[64 + t]);
    atomicAdd(&bnacc[512 + bn + t],  cq[t] + cq[64 + t]);
  }
}

// ======================= head =======================
__global__ __launch_bounds__(256) void k_head1(const float* __restrict__ c1,
    const float* __restrict__ c2, const float* __restrict__ Wl1,
    const float* __restrict__ bl1, float* __restrict__ t1){
  int g = blockIdx.y;
  int jj = threadIdx.x & 63, kc = threadIdx.x >> 6;
  int j = blockIdx.x*64 + jj;
  float acc = 0.f;
  for (int k = kc*256; k < kc*256 + 256; k++){
    float xg = c1[g*1024 + k] + c2[g*1024 + k];
    acc += xg * Wl1[(size_t)k*512 + j];
  }
  __shared__ float red[4][64];
  red[kc][jj] = acc;
  __syncthreads();
  if (kc == 0){
    float v = red[0][jj]+red[1][jj]+red[2][jj]+red[3][jj] + bl1[j];
    t1[g*512 + j] = fmaxf(v, 0.f);
  }
}
__global__ __launch_bounds__(256) void k_head2(const float* __restrict__ t1,
    const float* __restrict__ Wl2, const float* __restrict__ bl2, float* __restrict__ out){
  int g = blockIdx.y;
  int jj = threadIdx.x & 63, kc = threadIdx.x >> 6;
  int j = blockIdx.x*64 + jj;
  float acc = 0.f;
  for (int k = kc*128; k < kc*128 + 128; k++)
    acc += t1[g*512 + k] * Wl2[(size_t)k*256 + j];
  __shared__ float red[4][64];
  red[kc][jj] = acc;
  __syncthreads();
  if (kc == 0)
    out[g*256 + j] = red[0][jj]+red[1][jj]+red[2][jj]+red[3][jj] + bl2[j];
}

extern "C" void kernel_launch(void* const* d_in, const int* in_sizes, int n_in,
                              void* d_out, int out_size, void* d_ws, size_t ws_size,
                              hipStream_t stream){
  const float* x   = (const float*)d_in[0];
  const int*   ei  = (const int*)d_in[1];
  const float* W1  = (const float*)d_in[2];
  const float* as1 = (const float*)d_in[3];
  const float* ad1 = (const float*)d_in[4];
  const float* bc1 = (const float*)d_in[5];
  const float* Wh1 = (const float*)d_in[6];
  const float* bh1 = (const float*)d_in[7];
  const float* g1  = (const float*)d_in[8];
  const float* be1 = (const float*)d_in[9];
  const float* p1  = (const float*)d_in[10];
  const float* W2  = (const float*)d_in[11];
  const float* as2 = (const float*)d_in[12];
  const float* ad2 = (const float*)d_in[13];
  const float* bc2 = (const float*)d_in[14];
  const float* Wh2 = (const float*)d_in[15];
  const float* bh2 = (const float*)d_in[16];
  const float* g2  = (const float*)d_in[17];
  const float* be2 = (const float*)d_in[18];
  const float* p2  = (const float*)d_in[19];
  const float* Wl1 = (const float*)d_in[20];
  const float* bl1 = (const float*)d_in[21];
  const float* Wl2 = (const float*)d_in[22];
  const float* bl2 = (const float*)d_in[23];
  float* out = (float*)d_out;

  const int* src0 = ei;
  const int* tgt0 = ei + E_EDGES;

  // ---- workspace layout (unchanged offsets; some regions now unused/reused) ----
  bf16* Cc     = (bf16*)d_ws;                        // 8192*512 bf16 (h1 -> h2)
  bf16* xn1    = Cc + (size_t)NN1*EMB;               // 6560*512 bf16
  bf16* xn2    = xn1 + (size_t)NN2*EMB;              // (unused hole)
  float* aggx1 = (float*)(xn2 + (size_t)NG*KP2*EMB + 8); // 8192*9
  float* M1    = aggx1 + (size_t)NN1*9;              // 9*512
  float* was2  = M1 + 9*EMB;                         // 3*512
  float* wad2  = was2 + 3*EMB;
  float* cvec1 = wad2 + 3*EMB;                       // 512
  float* cvec2 = cvec1 + EMB;
  float* was1  = cvec2 + EMB;                        // 16
  float* wad1  = was1 + 16;
  float* bnpsum= wad1 + 16;                          // reused: bnacc1 (layer-1 BN sums)
  float* bnpsq = bnpsum + (size_t)BNCH*EMB;          // (unused hole)
  float* stats = bnpsq + (size_t)BNCH*EMB;           // 1024
  float* bnacc = stats + 1024;                       // 1024 (layer-2 direct sums)
  float* pn    = bnacc + 1024;                       // 16
  float* score = pn + 16;                            // 8192
  float* cat1  = score + NN1;                        // 16*1024
  float* cat2  = cat1 + NG*1024;
  float* t1h   = cat2 + NG*1024;                     // 16*512
  float* pmax  = t1h + NG*EMB;                       // (unused hole)
  float* psum  = pmax + NG*16*EMB;                   // (unused hole)
  float* aso2  = psum + NG*16*EMB;                   // 6560*3
  float* ado2  = aso2 + NN2*3;
  float* tops  = ado2 + NN2*3;                       // 16*410
  bf16* aggx2h = (bf16*)(tops + NG*KP1);             // 6560*1536 (bf16, hi only)
  bf16* M2Th   = aggx2h + (size_t)NN2*F1;            // 512*1536
  bf16* M2Tl   = M2Th + (size_t)EMB*F1;
  int* map     = (int*)(M2Tl + (size_t)EMB*F1);      // 8192
  int* cnt1    = map + NN1;
  int* off1    = cnt1 + NN1;                         // 8200
  int* cur1    = off1 + NN1 + 8;
  int* esrc1   = cur1 + NN1;                         // 139264
  int* cnt2    = esrc1 + (E_EDGES + NN1);
  int* off2    = cnt2 + NN2;                         // 6568
  int* cur2    = off2 + NN2 + 8;
  int* esrc2   = cur2 + NN2;                         // 137700 (pad)
  int* topi    = esrc2 + 137700;                     // 16*410

  float* bnacc1 = bnpsum;                            // layer-1 BN accumulator (1024 floats)

  // ---- precompute (fused) ----
  k_pre<<<84,256,0,stream>>>(W1,as1,ad1,Wh1,bc1,bh1, W2,as2,ad2,Wh2,bc2,bh2,
                             was1,wad1,M1,cvec1,cvec2,was2,wad2,
                             cnt1,cnt2,map,bnacc,bnacc1);
  k_gemm_s_mfma<<<dim3(8,8,3),256,0,stream>>>(W2,Wh2,M2Th,M2Tl);

  // ---- layer 1 ----
  k_count1<<<(E_EDGES+255)/256,256,0,stream>>>(tgt0,cnt1,E_EDGES);
  k_scan<<<1,1024,0,stream>>>(cnt1,off1,cur1,NN1);
  k_fill1<<<(E_EDGES+NN1+255)/256,256,0,stream>>>(src0,tgt0,cur1,esrc1,E_EDGES,NN1);
  k_agg1<<<NN1,64,0,stream>>>(x,off1,esrc1,was1,wad1,aggx1);
  k_h1<<<NN1/32,256,0,stream>>>(aggx1,M1,cvec1,Cc,bnacc1);
  k_bn_final_1<<<1,512,0,stream>>>(bnacc1,stats,NN1,p1,pn);
  k_score<<<NN1,256,0,stream>>>(Cc,stats,g1,be1,p1,pn,score);
  k_topk_sort<<<NG,512,0,stream>>>(score,map,topi,tops,NP1,KP1);
  k_topk_gather<<<NG*KP1,256,0,stream>>>(Cc,stats,g1,be1,topi,tops,xn1,NP1,KP1,
      was2,wad2,aso2,ado2);
  k_poolA<<<NG,512,0,stream>>>(xn1,cat1,KP1);

  // ---- layer 2 ----
  k_count2<<<(E_EDGES+255)/256,256,0,stream>>>(src0,tgt0,map,cnt2,E_EDGES);
  k_scan<<<1,1024,0,stream>>>(cnt2,off2,cur2,NN2);
  k_fill2<<<(E_EDGES+NN2+255)/256,256,0,stream>>>(src0,tgt0,map,cur2,esrc2,E_EDGES,NN2);
  k_agg2<<<NN2,256,0,stream>>>(xn1,aso2,ado2,off2,esrc2,aggx2h);
  k_gemm_mfma<<<52*8,256,0,stream>>>(aggx2h,M2Th,M2Tl,cvec2,Cc,bnacc,NN2,EMB,F1,52);
  k_bn_final_1<<<1,512,0,stream>>>(bnacc,stats,NN2,p2,pn+1);
  k_score<<<NN2,256,0,stream>>>(Cc,stats,g2,be2,p2,pn+1,score);
  k_topk_sort<<<NG,512,0,stream>>>(score,(int*)nullptr,topi,tops,KP1,KP2);
  k_poolB<<<NG,512,0,stream>>>(Cc,stats,g2,be2,topi,tops,cat2,KP1,KP2);

  // ---- head ----
  k_head1<<<dim3(8,NG),256,0,stream>>>(cat1,cat2,Wl1,bl1,t1h);
  k_head2<<<dim3(4,NG),256,0,stream>>>(t1h,Wl2,bl2,out);
}

// Round 2
// 377.240 us; speedup vs baseline: 1.1106x; 1.0924x over previous
//
#include <hip/hip_runtime.h>
#include <hip/hip_bf16.h>
#include <math.h>

#define E_EDGES 131072
#define NN1 8192
#define NN2 6560          // 16*410
#define NG 16
#define NP1 512
#define KP1 410
#define KP2 205
#define F1 1536
#define EMB 512
#define MAXDEG 256
#define BNCH 256          // (legacy sizing constant for ws layout)

typedef __hip_bfloat16 bf16;
typedef __attribute__((ext_vector_type(8))) short short8;
typedef __attribute__((ext_vector_type(4))) float f32x4;
typedef __attribute__((ext_vector_type(4))) unsigned short us4;

__device__ inline float wred64(float v){
  #pragma unroll
  for (int o = 32; o; o >>= 1) v += __shfl_down(v, o);
  return v;
}
__device__ inline float b2f_raw(unsigned short u){
  return __uint_as_float((unsigned)u << 16);
}
union BFU { bf16 b; unsigned short u; };
__device__ inline unsigned short f2u(float v){ BFU x; x.b = __float2bfloat16(v); return x.u; }

__device__ __forceinline__ void gld16(const void* g, void* l){
  __builtin_amdgcn_global_load_lds(
      (const __attribute__((address_space(1))) void*)g,
      (__attribute__((address_space(3))) void*)l, 16, 0, 0);
}

__device__ inline void split_store(float v, bf16* __restrict__ ph, bf16* __restrict__ pl){
  bf16 hi = __float2bfloat16(v);
  *ph = hi;
  *pl = __float2bfloat16(v - __bfloat162float(hi));
}

// shared tail: write mean/inv-sigma + pnorm
__device__ inline void bn_tail(float s, float q, int c, float* __restrict__ stats,
    int M, const float* __restrict__ p, float* __restrict__ pnout){
  float mean = s / (float)M;
  float var = fmaxf(q / (float)M - mean*mean, 0.f);
  stats[c] = mean;
  stats[512+c] = 1.f / sqrtf(var + 1e-5f);
  float v = p[c]; v = v*v;
  v = wred64(v);
  __shared__ float red[8];
  int lane = c & 63, wv = c >> 6;
  if (lane == 0) red[wv] = v;
  __syncthreads();
  if (c == 0){ float sm = 0.f; for (int i = 0; i < 8; i++) sm += red[i]; pnout[0] = sqrtf(sm); }
}

// ======================= fused per-launch precompute (latency-parallel) =======================
// blocks [0,24): M1 partials (h x jhalf x kchunk, 3 f-outputs each) -> M1p[4][9*512]
// [24,56): cvec partials (which x jhalf x kchunk8)                  -> cvp[16][512]
// [56,152): watt2 (y x 16 e-tiles, 1 row per wave, coalesced)
// [152,170): watt1      [170,202): init (cnt/map/bnacc)
__global__ __launch_bounds__(256) void k_pre(
    const float* __restrict__ W1, const float* __restrict__ as1, const float* __restrict__ ad1,
    const float* __restrict__ Wh1, const float* __restrict__ bc1, const float* __restrict__ bh1,
    const float* __restrict__ W2, const float* __restrict__ as2, const float* __restrict__ ad2,
    const float* __restrict__ Wh2, const float* __restrict__ bc2, const float* __restrict__ bh2,
    float* __restrict__ was1, float* __restrict__ wad1, float* __restrict__ M1p,
    float* __restrict__ cvp,
    float* __restrict__ was2, float* __restrict__ wad2,
    int* __restrict__ cnt1, int* __restrict__ cnt2, int* __restrict__ map,
    float* __restrict__ bnacc, float* __restrict__ bnacc1){
  int b = blockIdx.x, t = threadIdx.x;
  if (b < 24){                               // M1 partials, no atomics
    int h = b / 8, rem = b % 8, jh = rem >> 2, kc = rem & 3;
    int j = jh*256 + t, c0 = kc*128;
    __shared__ float w1s[3][128];
    for (int i = t; i < 384; i += 256)
      w1s[i>>7][i&127] = W1[(i>>7)*1536 + h*512 + c0 + (i&127)];
    __syncthreads();
    const float* whc = Wh1 + (size_t)(h*512 + c0)*512 + j;
    float a0=0.f, a1=0.f, a2=0.f;
    #pragma unroll 8
    for (int c = 0; c < 128; c++){
      float v = whc[(size_t)c*512];
      a0 += w1s[0][c]*v; a1 += w1s[1][c]*v; a2 += w1s[2][c]*v;
    }
    float* dst = M1p + (size_t)kc*4608;
    dst[(h*3+0)*512 + j] = a0;
    dst[(h*3+1)*512 + j] = a1;
    dst[(h*3+2)*512 + j] = a2;
  } else if (b < 56){                        // cvec partials
    int b2 = b - 24;
    int which = b2 >> 4, rem = b2 & 15, jh = rem >> 3, kc = rem & 7;
    const float* bc = which ? bc2 : bc1;
    const float* Wh = which ? Wh2 : Wh1;
    const float* bh = which ? bh2 : bh1;
    int j = jh*256 + t, i0 = kc*192;
    float acc = (kc == 0) ? bh[j] : 0.f;
    #pragma unroll 8
    for (int i = 0; i < 192; i++)
      acc += bc[i0+i] * Wh[(size_t)(i0+i)*512 + j];
    cvp[(size_t)(which*8 + kc)*512 + j] = acc;
  } else if (b < 152){                       // watt2: one contiguous row per wave
    int b3 = b - 56;
    int y = b3 >> 4, et = b3 & 15;
    int kind = y / 3, h = y % 3;
    int w = t >> 6, lane = t & 63;
    const float* att = kind ? ad2 : as2;
    float a[8];
    #pragma unroll
    for (int u = 0; u < 8; u++) a[u] = att[h*512 + lane*8 + u];
    for (int r = w; r < 32; r += 4){
      int e = et*32 + r;
      const float4* row = (const float4*)(W2 + (size_t)e*1536 + h*512) + lane*2;
      float4 v0 = row[0], v1 = row[1];
      float d = v0.x*a[0]+v0.y*a[1]+v0.z*a[2]+v0.w*a[3]
              + v1.x*a[4]+v1.y*a[5]+v1.z*a[6]+v1.w*a[7];
      d = wred64(d);
      if (lane == 0) (kind ? wad2 : was2)[h*512 + e] = d;
    }
  } else if (b < 170){                       // watt1 (1 wave active)
    if (t < 64){
      int bb = b - 152;
      int kind = bb / 9, r = bb % 9, h = r / 3, f = r % 3;
      const float* att = kind ? ad1 : as1;
      float s = 0.f;
      for (int c = t; c < 512; c += 64) s += W1[f*1536 + h*512 + c] * att[h*512 + c];
      s = wred64(s);
      if (t == 0) (kind ? wad1 : was1)[h*3 + f] = s;
    }
  } else {                                   // init
    int i = (b - 170)*256 + t;
    if (i < NN1){ cnt1[i] = 1; map[i] = -1; }
    if (i < NN2){ cnt2[i] = 1; }
    if (i < 1024){ bnacc[i] = 0.f; bnacc1[i] = 0.f; }
  }
}

// ======================= M2 precompute: bf16 3-pass split MFMA GEMM =======================
// C_z[m][n] = sum_k W2[m, z*512+k] * Wh2[z*512+k, n];  64x64 tile, BK=64, 256 thr (4 waves)
__global__ __launch_bounds__(256) void k_gemm_s_mfma(const float* __restrict__ A0,
    const float* __restrict__ B0, bf16* __restrict__ Th, bf16* __restrict__ Tl){
  int z = blockIdx.z;
  const float* A = A0 + (size_t)z*512;            // row stride 1536 (k-contig)
  const float* B = B0 + (size_t)z*512*512;        // row stride 512 (n-contig)
  __shared__ __align__(16) short sAh[4096], sAl[4096], sBh[4096], sBl[4096];
  int t = threadIdx.x, w = t >> 6, lane = t & 63;
  int l16 = lane & 15, q = lane >> 4;
  int bm = blockIdx.y*64, bn = blockIdx.x*64;

  int am  = t >> 2, akw = (t & 3)*16;             // A: row am, k window
  int bnl = t & 63, bkq = (t >> 6)*16;            // B: col bnl, k window

  f32x4 acc[4];
  #pragma unroll
  for (int nf = 0; nf < 4; nf++) acc[nf] = (f32x4){0.f,0.f,0.f,0.f};

  float va[16], vb[16];
  #define GS_LOAD(K0) do { \
    _Pragma("unroll") for (int u = 0; u < 4; u++){ \
      float4 v4 = *(const float4*)(A + (size_t)(bm+am)*1536 + (K0) + akw + u*4); \
      va[u*4]=v4.x; va[u*4+1]=v4.y; va[u*4+2]=v4.z; va[u*4+3]=v4.w; } \
    _Pragma("unroll") for (int u = 0; u < 16; u++) \
      vb[u] = B[(size_t)((K0) + bkq + u)*512 + bn + bnl]; \
  } while(0)

  GS_LOAD(0);
  for (int it = 0; it < 8; it++){
    #pragma unroll
    for (int hh = 0; hh < 2; hh++){
      short8 ah_, al_, bh_, bl_;
      #pragma unroll
      for (int jj = 0; jj < 8; jj++){
        float v = va[hh*8+jj];
        unsigned short hu = f2u(v);
        ah_[jj] = (short)hu; al_[jj] = (short)f2u(v - b2f_raw(hu));
        v = vb[hh*8+jj];
        hu = f2u(v);
        bh_[jj] = (short)hu; bl_[jj] = (short)f2u(v - b2f_raw(hu));
      }
      int aoff = am*64  + ((((akw>>3) + hh) ^ (am  & 7)) << 3);
      *(short8*)(sAh + aoff) = ah_;
      *(short8*)(sAl + aoff) = al_;
      int boff = bnl*64 + ((((bkq>>3) + hh) ^ (bnl & 7)) << 3);
      *(short8*)(sBh + boff) = bh_;
      *(short8*)(sBl + boff) = bl_;
    }
    __syncthreads();
    if (it < 7) GS_LOAD((it+1)*64);              // prefetch overlaps MFMA below
    #pragma unroll
    for (int ks = 0; ks < 2; ks++){
      int gc = ks*4 + q;
      int ar = w*16 + l16;
      int ao = ar*64 + ((gc ^ (ar & 7)) << 3);
      short8 afh = *(const short8*)(sAh + ao);
      short8 afl = *(const short8*)(sAl + ao);
      #pragma unroll
      for (int nf = 0; nf < 4; nf++){
        int br = nf*16 + l16;
        int bo = br*64 + ((gc ^ (br & 7)) << 3);
        short8 bfh = *(const short8*)(sBh + bo);
        short8 bfl = *(const short8*)(sBl + bo);
        acc[nf] = __builtin_amdgcn_mfma_f32_16x16x32_bf16(afh, bfh, acc[nf], 0, 0, 0);
        acc[nf] = __builtin_amdgcn_mfma_f32_16x16x32_bf16(afh, bfl, acc[nf], 0, 0, 0);
        acc[nf] = __builtin_amdgcn_mfma_f32_16x16x32_bf16(afl, bfh, acc[nf], 0, 0, 0);
      }
    }
    __syncthreads();
  }
  #undef GS_LOAD

  int m0 = bm + w*16 + q*4;
  #pragma unroll
  for (int nf = 0; nf < 4; nf++){
    int n = bn + nf*16 + l16;
    size_t base = (size_t)n*1536 + (size_t)z*512 + m0;
    #pragma unroll
    for (int e = 0; e < 4; e++)
      split_store(acc[nf][e], &Th[base+e], &Tl[base+e]);
  }
}

// ======================= CSR build =======================
__global__ void k_count1(const int* __restrict__ tgt0, int* __restrict__ cnt, int E){
  int i = blockIdx.x*blockDim.x + threadIdx.x;
  if (i < E) atomicAdd(&cnt[tgt0[i]], 1);
}
__global__ void k_count2(const int* __restrict__ src0, const int* __restrict__ tgt0,
                         const int* __restrict__ map, int* __restrict__ cnt, int E){
  int i = blockIdx.x*blockDim.x + threadIdx.x;
  if (i >= E) return;
  int s = map[src0[i]], tg = map[tgt0[i]];
  if (s >= 0 && tg >= 0) atomicAdd(&cnt[tg], 1);
}
__global__ __launch_bounds__(1024) void k_scan(const int* __restrict__ counts,
    int* __restrict__ off, int* __restrict__ cur, int n){
  __shared__ int sh[1024];
  int t = threadIdx.x;
  int chunk = (n + 1023) >> 10;
  int b = t * chunk; int e = b + chunk; if (e > n) e = n;
  int s = 0;
  for (int i = b; i < e && i < n; i++) s += counts[i];
  sh[t] = s; __syncthreads();
  for (int o = 1; o < 1024; o <<= 1){
    int v = (t >= o) ? sh[t-o] : 0;
    __syncthreads();
    sh[t] += v;
    __syncthreads();
  }
  int run = (t > 0) ? sh[t-1] : 0;
  for (int i = b; i < e && i < n; i++){ int c = counts[i]; off[i] = run; cur[i] = run; run += c; }
  if (t == 1023) off[n] = sh[1023];
}
__global__ void k_fill1(const int* __restrict__ src0, const int* __restrict__ tgt0,
                        int* __restrict__ cur, int* __restrict__ esrc, int E, int nn){
  int i = blockIdx.x*blockDim.x + threadIdx.x;
  if (i >= E + nn) return;
  int s, tg;
  if (i < E){ s = src0[i]; tg = tgt0[i]; } else { s = i - E; tg = s; }
  int pos = atomicAdd(&cur[tg], 1);
  esrc[pos] = s;
}
__global__ void k_fill2(const int* __restrict__ src0, const int* __restrict__ tgt0,
                        const int* __restrict__ map, int* __restrict__ cur,
                        int* __restrict__ esrc, int E, int nn){
  int i = blockIdx.x*blockDim.x + threadIdx.x;
  if (i >= E + nn) return;
  int s, tg;
  if (i < E){
    s = map[src0[i]]; tg = map[tgt0[i]];
    if (s < 0 || tg < 0) return;
  } else { s = i - E; tg = s; }
  int pos = atomicAdd(&cur[tg], 1);
  esrc[pos] = s;
}

// ======================= layer 1: aggregate raw x (3 features) =======================
__global__ __launch_bounds__(64) void k_agg1(
    const float* __restrict__ x, const int* __restrict__ off, const int* __restrict__ esrc,
    const float* __restrict__ was, const float* __restrict__ wad,
    float* __restrict__ aggx){          // [n*9], idx h*3+f
  int n = blockIdx.x, t = threadIdx.x;  // 64 threads = 1 wave
  __shared__ float xs[MAXDEG][3];
  __shared__ float al[MAXDEG*3];
  __shared__ float mh[3], dh[3];
  int s0 = off[n]; int deg = off[n+1] - s0; if (deg > MAXDEG) deg = MAXDEG;
  float ad0, ad1, ad2;
  {
    float x0 = x[n*3], x1 = x[n*3+1], x2 = x[n*3+2];
    ad0 = x0*wad[0] + x1*wad[1] + x2*wad[2];
    ad1 = x0*wad[3] + x1*wad[4] + x2*wad[5];
    ad2 = x0*wad[6] + x1*wad[7] + x2*wad[8];
  }
  for (int e = t; e < deg; e += 64){
    int s = esrc[s0 + e];
    float x0 = x[s*3], x1 = x[s*3+1], x2 = x[s*3+2];
    xs[e][0] = x0; xs[e][1] = x1; xs[e][2] = x2;
    float v0 = x0*was[0] + x1*was[1] + x2*was[2] + ad0;
    float v1 = x0*was[3] + x1*was[4] + x2*was[5] + ad1;
    float v2 = x0*was[6] + x1*was[7] + x2*was[8] + ad2;
    al[e*3+0] = v0 > 0.f ? v0 : 0.2f*v0;
    al[e*3+1] = v1 > 0.f ? v1 : 0.2f*v1;
    al[e*3+2] = v2 > 0.f ? v2 : 0.2f*v2;
  }
  __syncthreads();
  if (t < 3){
    float m = -INFINITY;
    for (int e = 0; e < deg; e++) m = fmaxf(m, al[e*3+t]);
    float d = 0.f;
    for (int e = 0; e < deg; e++) d += expf(al[e*3+t] - m);
    mh[t] = m; dh[t] = 1.f / fmaxf(d, 1e-16f);
  }
  __syncthreads();
  float acc[9] = {0,0,0,0,0,0,0,0,0};
  for (int e = t; e < deg; e += 64){
    #pragma unroll
    for (int h = 0; h < 3; h++){
      float a = expf(al[e*3+h] - mh[h]) * dh[h];
      acc[h*3+0] += a * xs[e][0];
      acc[h*3+1] += a * xs[e][1];
      acc[h*3+2] += a * xs[e][2];
    }
  }
  #pragma unroll
  for (int q = 0; q < 9; q++){
    float v = wred64(acc[q]);
    if (t == 0) aggx[(size_t)n*9 + q] = v;
  }
}

// h1[n,j] = relu(cvec[j] + sum_q aggx[n,q]*M1[q,j]) -> bf16 ; 32 nodes/block, fused BN partials
// M1/cvec arrive as K-chunk partials (M1p[4][9*512], cvp1[8][512]); reduce during LDS load.
__global__ __launch_bounds__(256) void k_h1(const float* __restrict__ aggx,
    const float* __restrict__ M1p, const float* __restrict__ cvp1, bf16* __restrict__ hout,
    float* __restrict__ bnacc1){
  __shared__ float sM[9*512];
  __shared__ float sC[512];
  __shared__ float sA[32*9];
  int t = threadIdx.x; int n0 = blockIdx.x*32;
  for (int i = t; i < 9*512; i += 256)
    sM[i] = M1p[i] + M1p[4608 + i] + M1p[2*4608 + i] + M1p[3*4608 + i];
  for (int i = t; i < 512; i += 256){
    float s = 0.f;
    #pragma unroll
    for (int kc = 0; kc < 8; kc++) s += cvp1[kc*512 + i];
    sC[i] = s;
  }
  for (int i = t; i < 288; i += 256) sA[i] = aggx[(size_t)n0*9 + i];
  __syncthreads();
  float c0v = sC[t], c1v = sC[t+256];
  float ls0=0.f, lq0=0.f, ls1=0.f, lq1=0.f;
  #pragma unroll 4
  for (int i = 0; i < 32; i++){
    float a0 = c0v, a1 = c1v;
    #pragma unroll
    for (int q = 0; q < 9; q++){
      float av = sA[i*9+q];
      a0 += av * sM[q*512 + t];
      a1 += av * sM[q*512 + t + 256];
    }
    a0 = fmaxf(a0, 0.f); a1 = fmaxf(a1, 0.f);
    hout[(size_t)(n0+i)*512 + t]       = __float2bfloat16(a0);
    hout[(size_t)(n0+i)*512 + t + 256] = __float2bfloat16(a1);
    ls0 += a0; lq0 += a0*a0; ls1 += a1; lq1 += a1*a1;
  }
  atomicAdd(&bnacc1[t],           ls0);
  atomicAdd(&bnacc1[t+256],       ls1);
  atomicAdd(&bnacc1[512 + t],     lq0);
  atomicAdd(&bnacc1[512 + t+256], lq1);
}

// ======================= BN / score =======================
__global__ void k_bn_final_1(const float* __restrict__ bnacc,
    float* __restrict__ stats, int M, const float* __restrict__ p, float* __restrict__ pnout){
  int c = threadIdx.x;
  bn_tail(bnacc[c], bnacc[512 + c], c, stats, M, p, pnout);
}
__global__ __launch_bounds__(256) void k_score(
    const bf16* __restrict__ h, const float* __restrict__ stats,
    const float* __restrict__ g_, const float* __restrict__ be,
    const float* __restrict__ p, const float* __restrict__ pn,
    float* __restrict__ score){
  int r = blockIdx.x, t = threadIdx.x;
  float dot = 0.f;
  #pragma unroll
  for (int k = 0; k < 2; k++){
    int c = t + k*256;
    float v = (__bfloat162float(h[(size_t)r*EMB + c]) - stats[c]) * stats[512+c] * g_[c] + be[c];
    dot += v * p[c];
  }
  dot = wred64(dot);
  __shared__ float red[4];
  int lane = t & 63, wv = t >> 6;
  if (lane == 0) red[wv] = dot;
  __syncthreads();
  if (t == 0) score[r] = tanhf((red[0]+red[1]+red[2]+red[3]) / pn[0]);
}

// ======================= top-k =======================
__global__ __launch_bounds__(512) void k_topk_sort(
    const float* __restrict__ score, int* __restrict__ map,
    int* __restrict__ topi, float* __restrict__ tops, int n_per, int K){
  int g = blockIdx.x, t = threadIdx.x;     // 512 threads, 1 elem each
  __shared__ float sk[512];
  __shared__ int si[512];
  if (t < n_per){ sk[t] = score[g*n_per + t]; si[t] = t; }
  else { sk[t] = -INFINITY; si[t] = 0x7fffffff; }
  __syncthreads();
  for (int k = 2; k <= 512; k <<= 1){
    for (int j = k >> 1; j > 0; j >>= 1){
      int l = t ^ j;
      if (l > t){
        float ki = sk[t], kl = sk[l]; int ii = si[t], il = si[l];
        bool before_l = (kl > ki) || (kl == ki && il < ii);
        bool up = ((t & k) == 0);
        if (up == before_l){ sk[t]=kl; sk[l]=ki; si[t]=il; si[l]=ii; }
      }
      __syncthreads();
    }
  }
  if (t < K){
    if (map) map[g*n_per + si[t]] = g*K + t;
    topi[g*K + t] = si[t];
    tops[g*K + t] = sk[t];
  }
}

// gather + on-the-fly BN + scale -> bf16; fused layer-2 attention dots
__global__ __launch_bounds__(256) void k_topk_gather(
    const bf16* __restrict__ h, const float* __restrict__ stats,
    const float* __restrict__ gm, const float* __restrict__ be,
    const int* __restrict__ topi, const float* __restrict__ tops,
    bf16* __restrict__ xn, int n_per, int K,
    const float* __restrict__ was2, const float* __restrict__ wad2,
    float* __restrict__ aso, float* __restrict__ ado){
  int row = blockIdx.x, t = threadIdx.x;
  int gr = row / K, i = row - gr*K;
  int sidx = topi[gr*K + i];
  float s = tops[gr*K + i];
  const bf16* src = h + ((size_t)(gr*n_per + sidx))*EMB;
  bf16* dst = xn + (size_t)row*EMB;
  int c0 = t, c1 = t + 256;
  float v0 = ((__bfloat162float(src[c0]) - stats[c0]) * stats[512+c0] * gm[c0] + be[c0]) * s;
  float v1 = ((__bfloat162float(src[c1]) - stats[c1]) * stats[512+c1] * gm[c1] + be[c1]) * s;
  dst[c0] = __float2bfloat16(v0);
  dst[c1] = __float2bfloat16(v1);
  if (was2){
    float a[6];
    #pragma unroll
    for (int hh = 0; hh < 3; hh++){
      a[hh]   = v0*was2[hh*512 + c0] + v1*was2[hh*512 + c1];
      a[3+hh] = v0*wad2[hh*512 + c0] + v1*wad2[hh*512 + c1];
    }
    __shared__ float red[6][4];
    int lane = t & 63, wv = t >> 6;
    #pragma unroll
    for (int q = 0; q < 6; q++){ float v = wred64(a[q]); if (lane==0) red[q][wv]=v; }
    __syncthreads();
    if (t < 6){
      float sm = red[t][0]+red[t][1]+red[t][2]+red[t][3];
      if (t < 3) aso[row*3+t] = sm; else ado[row*3+(t-3)] = sm;
    }
  }
}

// ======================= pooling =======================
__global__ __launch_bounds__(512) void k_poolA(const bf16* __restrict__ xn,
    float* __restrict__ cat, int K){
  int g = blockIdx.x, c = threadIdx.x;
  const unsigned short* p = (const unsigned short*)xn + (size_t)g*K*EMB + c;
  float mx = -INFINITY, sm = 0.f;
  #pragma unroll 4
  for (int r = 0; r < K; r++){
    float v = b2f_raw(p[(size_t)r*EMB]);
    mx = fmaxf(mx, v); sm += v;
  }
  cat[g*1024 + c] = mx;
  cat[g*1024 + 512 + c] = sm / (float)K;
}
__global__ __launch_bounds__(512) void k_poolB(const bf16* __restrict__ h,
    const float* __restrict__ stats, const float* __restrict__ gm, const float* __restrict__ be,
    const int* __restrict__ topi, const float* __restrict__ tops,
    float* __restrict__ cat, int n_per, int K){
  int g = blockIdx.x, c = threadIdx.x;
  __shared__ int sti[256];
  __shared__ float sts[256];
  for (int r = c; r < K; r += 512){ sti[r] = topi[g*K + r]; sts[r] = tops[g*K + r]; }
  __syncthreads();
  float mean = stats[c], inv = stats[512+c];
  float gg = gm[c], bb = be[c];
  const unsigned short* hp = (const unsigned short*)h;
  float mx = -INFINITY, sm = 0.f;
  #pragma unroll 4
  for (int r = 0; r < K; r++){
    float v = (b2f_raw(hp[(size_t)(g*n_per + sti[r])*EMB + c]) - mean) * inv * gg + bb;
    v *= sts[r];
    mx = fmaxf(mx, v); sm += v;
  }
  cat[g*1024 + c] = mx;
  cat[g*1024 + 512 + c] = sm / (float)K;
}

// ======================= layer 2 aggregation (bf16 xn input) =======================
__global__ __launch_bounds__(256) void k_agg2(
    const bf16* __restrict__ xn, const float* __restrict__ aso, const float* __restrict__ ado,
    const int* __restrict__ off, const int* __restrict__ esrc,
    bf16* __restrict__ oh){
  int n = blockIdx.x, t = threadIdx.x;
  __shared__ int srcs[MAXDEG];
  __shared__ float al[MAXDEG*3];
  __shared__ float mh[3], dh[3];
  int s0 = off[n]; int deg = off[n+1] - s0; if (deg > MAXDEG) deg = MAXDEG;
  for (int e = t; e < deg; e += 256) srcs[e] = esrc[s0 + e];
  __syncthreads();
  float ad0 = ado[n*3+0], ad1 = ado[n*3+1], ad2 = ado[n*3+2];
  for (int e = t; e < deg; e += 256){
    int s = srcs[e];
    float v0 = aso[s*3+0] + ad0, v1 = aso[s*3+1] + ad1, v2 = aso[s*3+2] + ad2;
    al[e*3+0] = v0 > 0.f ? v0 : 0.2f*v0;
    al[e*3+1] = v1 > 0.f ? v1 : 0.2f*v1;
    al[e*3+2] = v2 > 0.f ? v2 : 0.2f*v2;
  }
  __syncthreads();
  if (t < 3){
    float m = -INFINITY;
    for (int e = 0; e < deg; e++) m = fmaxf(m, al[e*3+t]);
    float d = 0.f;
    for (int e = 0; e < deg; e++) d += expf(al[e*3+t] - m);
    mh[t] = m; dh[t] = 1.f / fmaxf(d, 1e-16f);
  }
  __syncthreads();
  for (int e = t; e < deg; e += 256){
    al[e*3+0] = expf(al[e*3+0]-mh[0])*dh[0];
    al[e*3+1] = expf(al[e*3+1]-mh[1])*dh[1];
    al[e*3+2] = expf(al[e*3+2]-mh[2])*dh[2];
  }
  __syncthreads();
  float acc[2][3] = {};
  for (int e = 0; e < deg; e++){
    int s = srcs[e];
    float a0 = al[e*3], a1 = al[e*3+1], a2 = al[e*3+2];
    #pragma unroll
    for (int k = 0; k < 2; k++){
      float v = __bfloat162float(xn[(size_t)s*512 + t + k*256]);
      acc[k][0] += a0*v; acc[k][1] += a1*v; acc[k][2] += a2*v;
    }
  }
  #pragma unroll
  for (int k = 0; k < 2; k++){
    int c = t + k*256;
    #pragma unroll
    for (int h = 0; h < 3; h++)
      oh[(size_t)n*1536 + h*512 + c] = __float2bfloat16(acc[k][h]);
  }
}

// ======================= bf16-A x split-bf16-B MFMA GEMM =======================
// bias arrives as 8 K-chunk partials (cvp2[8][512]); summed at epilogue.
__global__ __launch_bounds__(256, 2) void k_gemm_mfma(
    const bf16* __restrict__ Ah,
    const bf16* __restrict__ Bh, const bf16* __restrict__ Bl,   // [N][K] row-major
    const float* __restrict__ bias, bf16* __restrict__ C,
    float* __restrict__ bnacc,
    int M, int N, int K, int Mtiles){
  __shared__ __align__(16) unsigned short lds[2][16384];   // 64 KB total
  int t = threadIdx.x, w = t >> 6, lane = t & 63;
  int q = lane >> 4, l16 = lane & 15;
  int bmi = (int)blockIdx.x % Mtiles, bni = (int)blockIdx.x / Mtiles;
  int bm = bmi * 128, bn = bni * 64;

  int lr = lane >> 3, lc = lane & 7;
  int kg = ((lc ^ lr) & 7) * 8;          // swizzled global k element offset
  int ro = w*8 + lr;
  int m0 = bm + ro, m1 = bm + 32 + ro, m2 = bm + 64 + ro, m3 = bm + 96 + ro;
  if (m0 >= M) m0 = M-1;  if (m1 >= M) m1 = M-1;
  if (m2 >= M) m2 = M-1;  if (m3 >= M) m3 = M-1;
  int n0 = bn + ro, n1 = bn + 32 + ro;
  const bf16* ptr[8];
  ptr[0] = Ah + (size_t)m0*K + kg;
  ptr[1] = Ah + (size_t)m1*K + kg;
  ptr[2] = Ah + (size_t)m2*K + kg;
  ptr[3] = Ah + (size_t)m3*K + kg;
  ptr[4] = Bh + (size_t)n0*K + kg;
  ptr[5] = Bh + (size_t)n1*K + kg;
  ptr[6] = Bl + (size_t)n0*K + kg;
  ptr[7] = Bl + (size_t)n1*K + kg;
  const int dof[8] = {0, 2048, 4096, 6144, 8192, 10240, 12288, 14336};

  int wm = (w >> 1) * 64, wn = (w & 1) * 32;
  f32x4 acc[4][2];
  #pragma unroll
  for (int i = 0; i < 4; i++)
    #pragma unroll
    for (int j = 0; j < 2; j++)
      acc[i][j] = (f32x4){0.f, 0.f, 0.f, 0.f};

  #pragma unroll
  for (int u = 0; u < 8; u++){
    gld16(ptr[u], &lds[0][dof[u] + w*512]);
    ptr[u] += 64;
  }

  int nit = K >> 6;
  for (int it = 0; it < nit; it++){
    __syncthreads();
    int cur = it & 1;
    if (it + 1 < nit){
      int nxt = cur ^ 1;
      #pragma unroll
      for (int u = 0; u < 8; u++){
        gld16(ptr[u], &lds[nxt][dof[u] + w*512]);
        ptr[u] += 64;
      }
    }
    const unsigned short* L = lds[cur];
    #pragma unroll
    for (int ks = 0; ks < 2; ks++){
      short8 ah[4], bh2[2], bl2[2];
      int gc = ks*4 + q;
      #pragma unroll
      for (int i = 0; i < 4; i++){
        int r = wm + i*16 + l16;
        ah[i] = *(const short8*)(L + r*64 + ((gc ^ (r & 7)) << 3));
      }
      #pragma unroll
      for (int j = 0; j < 2; j++){
        int r = wn + j*16 + l16;
        int so = ((gc ^ (r & 7)) << 3);
        bh2[j] = *(const short8*)(L + 8192  + r*64 + so);
        bl2[j] = *(const short8*)(L + 12288 + r*64 + so);
      }
      #pragma unroll
      for (int i = 0; i < 4; i++)
        #pragma unroll
        for (int j = 0; j < 2; j++){
          acc[i][j] = __builtin_amdgcn_mfma_f32_16x16x32_bf16(ah[i], bh2[j], acc[i][j], 0, 0, 0);
          acc[i][j] = __builtin_amdgcn_mfma_f32_16x16x32_bf16(ah[i], bl2[j], acc[i][j], 0, 0, 0);
        }
    }
  }

  // epilogue: relu + bf16 store + per-column BN partials
  __syncthreads();                       // LDS now free for reduction scratch
  float* cs = (float*)&lds[0][0];        // [2][64] col sums | [2][64] col sqs
  float* cq = cs + 128;
  int slot = w >> 1;
  #pragma unroll
  for (int j = 0; j < 2; j++){
    int c_local = wn + j*16 + l16;
    int c = bn + c_local;
    float bv = 0.f;
    if (bias){
      #pragma unroll
      for (int kc = 0; kc < 8; kc++) bv += bias[kc*512 + c];
    }
    float ls = 0.f, lq = 0.f;
    #pragma unroll
    for (int i = 0; i < 4; i++){
      int rb = bm + wm + i*16 + q*4;
      #pragma unroll
      for (int e = 0; e < 4; e++){
        int r = rb + e;
        if (r < M){
          float v = fmaxf(acc[i][j][e] + bv, 0.f);
          C[(size_t)r*N + c] = __float2bfloat16(v);
          ls += v; lq += v*v;
        }
      }
    }
    ls += __shfl_xor(ls, 16); ls += __shfl_xor(ls, 32);
    lq += __shfl_xor(lq, 16); lq += __shfl_xor(lq, 32);
    if (q == 0){ cs[slot*64 + c_local] = ls; cq[slot*64 + c_local] = lq; }
  }
  __syncthreads();
  if (t < 64){
    atomicAdd(&bnacc[bn + t],        cs[t] + cs[64 + t]);
    atomicAdd(&bnacc[512 + bn + t],  cq[t] + cq[64 + t]);
  }
}

// ======================= head =======================
__global__ __launch_bounds__(256) void k_head1(const float* __restrict__ c1,
    const float* __restrict__ c2, const float* __restrict__ Wl1,
    const float* __restrict__ bl1, float* __restrict__ t1){
  int g = blockIdx.y;
  int jj = threadIdx.x & 63, kc = threadIdx.x >> 6;
  int j = blockIdx.x*64 + jj;
  float acc = 0.f;
  for (int k = kc*256; k < kc*256 + 256; k++){
    float xg = c1[g*1024 + k] + c2[g*1024 + k];
    acc += xg * Wl1[(size_t)k*512 + j];
  }
  __shared__ float red[4][64];
  red[kc][jj] = acc;
  __syncthreads();
  if (kc == 0){
    float v = red[0][jj]+red[1][jj]+red[2][jj]+red[3][jj] + bl1[j];
    t1[g*512 + j] = fmaxf(v, 0.f);
  }
}
__global__ __launch_bounds__(256) void k_head2(const float* __restrict__ t1,
    const float* __restrict__ Wl2, const float* __restrict__ bl2, float* __restrict__ out){
  int g = blockIdx.y;
  int jj = threadIdx.x & 63, kc = threadIdx.x >> 6;
  int j = blockIdx.x*64 + jj;
  float acc = 0.f;
  for (int k = kc*128; k < kc*128 + 128; k++)
    acc += t1[g*512 + k] * Wl2[(size_t)k*256 + j];
  __shared__ float red[4][64];
  red[kc][jj] = acc;
  __syncthreads();
  if (kc == 0)
    out[g*256 + j] = red[0][jj]+red[1][jj]+red[2][jj]+red[3][jj] + bl2[j];
}

extern "C" void kernel_launch(void* const* d_in, const int* in_sizes, int n_in,
                              void* d_out, int out_size, void* d_ws, size_t ws_size,
                              hipStream_t stream){
  const float* x   = (const float*)d_in[0];
  const int*   ei  = (const int*)d_in[1];
  const float* W1  = (const float*)d_in[2];
  const float* as1 = (const float*)d_in[3];
  const float* ad1 = (const float*)d_in[4];
  const float* bc1 = (const float*)d_in[5];
  const float* Wh1 = (const float*)d_in[6];
  const float* bh1 = (const float*)d_in[7];
  const float* g1  = (const float*)d_in[8];
  const float* be1 = (const float*)d_in[9];
  const float* p1  = (const float*)d_in[10];
  const float* W2  = (const float*)d_in[11];
  const float* as2 = (const float*)d_in[12];
  const float* ad2 = (const float*)d_in[13];
  const float* bc2 = (const float*)d_in[14];
  const float* Wh2 = (const float*)d_in[15];
  const float* bh2 = (const float*)d_in[16];
  const float* g2  = (const float*)d_in[17];
  const float* be2 = (const float*)d_in[18];
  const float* p2  = (const float*)d_in[19];
  const float* Wl1 = (const float*)d_in[20];
  const float* bl1 = (const float*)d_in[21];
  const float* Wl2 = (const float*)d_in[22];
  const float* bl2 = (const float*)d_in[23];
  float* out = (float*)d_out;

  const int* src0 = ei;
  const int* tgt0 = ei + E_EDGES;

  // ---- workspace layout ----
  bf16* Cc     = (bf16*)d_ws;                        // 8192*512 bf16 (h1 -> h2)
  bf16* xn1    = Cc + (size_t)NN1*EMB;               // 6560*512 bf16
  bf16* xn2    = xn1 + (size_t)NN2*EMB;              // (unused hole)
  float* aggx1 = (float*)(xn2 + (size_t)NG*KP2*EMB + 8); // 8192*9
  float* M1    = aggx1 + (size_t)NN1*9;              // (unused)
  float* was2  = M1 + 9*EMB;                         // 3*512
  float* wad2  = was2 + 3*EMB;
  float* cvec1 = wad2 + 3*EMB;                       // (unused)
  float* cvec2 = cvec1 + EMB;
  float* was1  = cvec2 + EMB;                        // 16
  float* wad1  = was1 + 16;
  float* bnpsum= wad1 + 16;                          // reused: bnacc1 (layer-1 BN sums)
  float* bnpsq = bnpsum + (size_t)BNCH*EMB;          // reused: M1p + cvp
  float* stats = bnpsq + (size_t)BNCH*EMB;           // 1024
  float* bnacc = stats + 1024;                       // 1024 (layer-2 direct sums)
  float* pn    = bnacc + 1024;                       // 16
  float* score = pn + 16;                            // 8192
  float* cat1  = score + NN1;                        // 16*1024
  float* cat2  = cat1 + NG*1024;
  float* t1h   = cat2 + NG*1024;                     // 16*512
  float* pmax  = t1h + NG*EMB;                       // (unused hole)
  float* psum  = pmax + NG*16*EMB;                   // (unused hole)
  float* aso2  = psum + NG*16*EMB;                   // 6560*3
  float* ado2  = aso2 + NN2*3;
  float* tops  = ado2 + NN2*3;                       // 16*410
  bf16* aggx2h = (bf16*)(tops + NG*KP1);             // 6560*1536 (bf16, hi only)
  bf16* M2Th   = aggx2h + (size_t)NN2*F1;            // 512*1536
  bf16* M2Tl   = M2Th + (size_t)EMB*F1;
  int* map     = (int*)(M2Tl + (size_t)EMB*F1);      // 8192
  int* cnt1    = map + NN1;
  int* off1    = cnt1 + NN1;                         // 8200
  int* cur1    = off1 + NN1 + 8;
  int* esrc1   = cur1 + NN1;                         // 139264
  int* cnt2    = esrc1 + (E_EDGES + NN1);
  int* off2    = cnt2 + NN2;                         // 6568
  int* cur2    = off2 + NN2 + 8;
  int* esrc2   = cur2 + NN2;                         // 137700 (pad)
  int* topi    = esrc2 + 137700;                     // 16*410

  float* bnacc1 = bnpsum;                            // layer-1 BN accumulator (1024 floats)
  float* M1p    = bnpsq;                             // 4*4608 floats (M1 K-chunk partials)
  float* cvp    = bnpsq + 4*4608;                    // 16*512 floats (cvec K-chunk partials)
  float* cvp2   = cvp + 8*512;                       // which=1 region (layer-2 bias partials)

  // ---- precompute (fused, latency-parallel) ----
  k_pre<<<202,256,0,stream>>>(W1,as1,ad1,Wh1,bc1,bh1, W2,as2,ad2,Wh2,bc2,bh2,
                              was1,wad1,M1p,cvp,was2,wad2,
                              cnt1,cnt2,map,bnacc,bnacc1);
  k_gemm_s_mfma<<<dim3(8,8,3),256,0,stream>>>(W2,Wh2,M2Th,M2Tl);

  // ---- layer 1 ----
  k_count1<<<(E_EDGES+255)/256,256,0,stream>>>(tgt0,cnt1,E_EDGES);
  k_scan<<<1,1024,0,stream>>>(cnt1,off1,cur1,NN1);
  k_fill1<<<(E_EDGES+NN1+255)/256,256,0,stream>>>(src0,tgt0,cur1,esrc1,E_EDGES,NN1);
  k_agg1<<<NN1,64,0,stream>>>(x,off1,esrc1,was1,wad1,aggx1);
  k_h1<<<NN1/32,256,0,stream>>>(aggx1,M1p,cvp,Cc,bnacc1);
  k_bn_final_1<<<1,512,0,stream>>>(bnacc1,stats,NN1,p1,pn);
  k_score<<<NN1,256,0,stream>>>(Cc,stats,g1,be1,p1,pn,score);
  k_topk_sort<<<NG,512,0,stream>>>(score,map,topi,tops,NP1,KP1);
  k_topk_gather<<<NG*KP1,256,0,stream>>>(Cc,stats,g1,be1,topi,tops,xn1,NP1,KP1,
      was2,wad2,aso2,ado2);
  k_poolA<<<NG,512,0,stream>>>(xn1,cat1,KP1);

  // ---- layer 2 ----
  k_count2<<<(E_EDGES+255)/256,256,0,stream>>>(src0,tgt0,map,cnt2,E_EDGES);
  k_scan<<<1,1024,0,stream>>>(cnt2,off2,cur2,NN2);
  k_fill2<<<(E_EDGES+NN2+255)/256,256,0,stream>>>(src0,tgt0,map,cur2,esrc2,E_EDGES,NN2);
  k_agg2<<<NN2,256,0,stream>>>(xn1,aso2,ado2,off2,esrc2,aggx2h);
  k_gemm_mfma<<<52*8,256,0,stream>>>(aggx2h,M2Th,M2Tl,cvp2,Cc,bnacc,NN2,EMB,F1,52);
  k_bn_final_1<<<1,512,0,stream>>>(bnacc,stats,NN2,p2,pn+1);
  k_score<<<NN2,256,0,stream>>>(Cc,stats,g2,be2,p2,pn+1,score);
  k_topk_sort<<<NG,512,0,stream>>>(score,(int*)nullptr,topi,tops,KP1,KP2);
  k_poolB<<<NG,512,0,stream>>>(Cc,stats,g2,be2,topi,tops,cat2,KP1,KP2);

  // ---- head ----
  k_head1<<<dim3(8,NG),256,0,stream>>>(cat1,cat2,Wl1,bl1,t1h);
  k_head2<<<dim3(4,NG),256,0,stream>>>(t1h,Wl2,bl2,out);
}

// Round 3
// 341.093 us; speedup vs baseline: 1.2282x; 1.1060x over previous
//
#include <hip/hip_runtime.h>
#include <hip/hip_bf16.h>
#include <math.h>

#define E_EDGES 131072
#define NN1 8192
#define NN2 6560          // 16*410
#define NG 16
#define NP1 512
#define KP1 410
#define KP2 205
#define F1 1536
#define EMB 512
#define MAXDEG 256
#define BNCH 256          // (legacy sizing constant for ws layout)

typedef __hip_bfloat16 bf16;
typedef __attribute__((ext_vector_type(8))) short short8;
typedef __attribute__((ext_vector_type(4))) float f32x4;
typedef __attribute__((ext_vector_type(4))) unsigned short us4;

__device__ inline float wred64(float v){
  #pragma unroll
  for (int o = 32; o; o >>= 1) v += __shfl_down(v, o);
  return v;
}
__device__ inline float b2f_raw(unsigned short u){
  return __uint_as_float((unsigned)u << 16);
}
union BFU { bf16 b; unsigned short u; };
__device__ inline unsigned short f2u(float v){ BFU x; x.b = __float2bfloat16(v); return x.u; }

__device__ __forceinline__ void gld16(const void* g, void* l){
  __builtin_amdgcn_global_load_lds(
      (const __attribute__((address_space(1))) void*)g,
      (__attribute__((address_space(3))) void*)l, 16, 0, 0);
}

__device__ inline void split_store(float v, bf16* __restrict__ ph, bf16* __restrict__ pl){
  bf16 hi = __float2bfloat16(v);
  *ph = hi;
  *pl = __float2bfloat16(v - __bfloat162float(hi));
}

// inline BN stats from raw sums (matches bn_tail formulas exactly)
__device__ inline void bn_from_acc(const float* __restrict__ bnacc, int c, float fM,
                                   float& mean, float& inv){
  mean = bnacc[c] / fM;
  float var = fmaxf(bnacc[512+c]/fM - mean*mean, 0.f);
  inv = 1.f / sqrtf(var + 1e-5f);
}

// ======================= fused per-launch precompute (latency-parallel) =======================
// blocks [0,24): M1 partials   [24,56): cvec partials   [56,152): watt2
// [152,170): watt1             [170,202): init (cnt/map/bnacc)
__global__ __launch_bounds__(256) void k_pre(
    const float* __restrict__ W1, const float* __restrict__ as1, const float* __restrict__ ad1,
    const float* __restrict__ Wh1, const float* __restrict__ bc1, const float* __restrict__ bh1,
    const float* __restrict__ W2, const float* __restrict__ as2, const float* __restrict__ ad2,
    const float* __restrict__ Wh2, const float* __restrict__ bc2, const float* __restrict__ bh2,
    float* __restrict__ was1, float* __restrict__ wad1, float* __restrict__ M1p,
    float* __restrict__ cvp,
    float* __restrict__ was2, float* __restrict__ wad2,
    int* __restrict__ cnt1, int* __restrict__ cnt2, int* __restrict__ map,
    float* __restrict__ bnacc, float* __restrict__ bnacc1){
  int b = blockIdx.x, t = threadIdx.x;
  if (b < 24){                               // M1 partials, no atomics
    int h = b / 8, rem = b % 8, jh = rem >> 2, kc = rem & 3;
    int j = jh*256 + t, c0 = kc*128;
    __shared__ float w1s[3][128];
    for (int i = t; i < 384; i += 256)
      w1s[i>>7][i&127] = W1[(i>>7)*1536 + h*512 + c0 + (i&127)];
    __syncthreads();
    const float* whc = Wh1 + (size_t)(h*512 + c0)*512 + j;
    float a0=0.f, a1=0.f, a2=0.f;
    #pragma unroll 8
    for (int c = 0; c < 128; c++){
      float v = whc[(size_t)c*512];
      a0 += w1s[0][c]*v; a1 += w1s[1][c]*v; a2 += w1s[2][c]*v;
    }
    float* dst = M1p + (size_t)kc*4608;
    dst[(h*3+0)*512 + j] = a0;
    dst[(h*3+1)*512 + j] = a1;
    dst[(h*3+2)*512 + j] = a2;
  } else if (b < 56){                        // cvec partials
    int b2 = b - 24;
    int which = b2 >> 4, rem = b2 & 15, jh = rem >> 3, kc = rem & 7;
    const float* bc = which ? bc2 : bc1;
    const float* Wh = which ? Wh2 : Wh1;
    const float* bh = which ? bh2 : bh1;
    int j = jh*256 + t, i0 = kc*192;
    float acc = (kc == 0) ? bh[j] : 0.f;
    #pragma unroll 8
    for (int i = 0; i < 192; i++)
      acc += bc[i0+i] * Wh[(size_t)(i0+i)*512 + j];
    cvp[(size_t)(which*8 + kc)*512 + j] = acc;
  } else if (b < 152){                       // watt2: one contiguous row per wave
    int b3 = b - 56;
    int y = b3 >> 4, et = b3 & 15;
    int kind = y / 3, h = y % 3;
    int w = t >> 6, lane = t & 63;
    const float* att = kind ? ad2 : as2;
    float a[8];
    #pragma unroll
    for (int u = 0; u < 8; u++) a[u] = att[h*512 + lane*8 + u];
    for (int r = w; r < 32; r += 4){
      int e = et*32 + r;
      const float4* row = (const float4*)(W2 + (size_t)e*1536 + h*512) + lane*2;
      float4 v0 = row[0], v1 = row[1];
      float d = v0.x*a[0]+v0.y*a[1]+v0.z*a[2]+v0.w*a[3]
              + v1.x*a[4]+v1.y*a[5]+v1.z*a[6]+v1.w*a[7];
      d = wred64(d);
      if (lane == 0) (kind ? wad2 : was2)[h*512 + e] = d;
    }
  } else if (b < 170){                       // watt1 (1 wave active)
    if (t < 64){
      int bb = b - 152;
      int kind = bb / 9, r = bb % 9, h = r / 3, f = r % 3;
      const float* att = kind ? ad1 : as1;
      float s = 0.f;
      for (int c = t; c < 512; c += 64) s += W1[f*1536 + h*512 + c] * att[h*512 + c];
      s = wred64(s);
      if (t == 0) (kind ? wad1 : was1)[h*3 + f] = s;
    }
  } else {                                   // init
    int i = (b - 170)*256 + t;
    if (i < NN1){ cnt1[i] = 1; map[i] = -1; }
    if (i < NN2){ cnt2[i] = 1; }
    if (i < 1024){ bnacc[i] = 0.f; bnacc1[i] = 0.f; }
  }
}

// ======================= M2 precompute GEMM + fused count1 =======================
// blocks [0,192): 64x64 split-bf16 MFMA tiles; [192,704): count1 atomics.
__global__ __launch_bounds__(256) void k_gemm_s_c1(const float* __restrict__ A0,
    const float* __restrict__ B0, bf16* __restrict__ Th, bf16* __restrict__ Tl,
    const int* __restrict__ tgt0, int* __restrict__ cnt1){
  int b = blockIdx.x;
  if (b >= 192){
    int i = (b - 192)*256 + threadIdx.x;
    if (i < E_EDGES) atomicAdd(&cnt1[tgt0[i]], 1);
    return;
  }
  int z = b % 3; int rr = b / 3; int by = rr >> 3, bx = rr & 7;
  const float* A = A0 + (size_t)z*512;            // row stride 1536 (k-contig)
  const float* B = B0 + (size_t)z*512*512;        // row stride 512 (n-contig)
  __shared__ __align__(16) short sAh[4096], sAl[4096], sBh[4096], sBl[4096];
  int t = threadIdx.x, w = t >> 6, lane = t & 63;
  int l16 = lane & 15, q = lane >> 4;
  int bm = by*64, bn = bx*64;

  int am  = t >> 2, akw = (t & 3)*16;             // A: row am, k window
  int bnl = t & 63, bkq = (t >> 6)*16;            // B: col bnl, k window

  f32x4 acc[4];
  #pragma unroll
  for (int nf = 0; nf < 4; nf++) acc[nf] = (f32x4){0.f,0.f,0.f,0.f};

  float va[16], vb[16];
  #define GS_LOAD(K0) do { \
    _Pragma("unroll") for (int u = 0; u < 4; u++){ \
      float4 v4 = *(const float4*)(A + (size_t)(bm+am)*1536 + (K0) + akw + u*4); \
      va[u*4]=v4.x; va[u*4+1]=v4.y; va[u*4+2]=v4.z; va[u*4+3]=v4.w; } \
    _Pragma("unroll") for (int u = 0; u < 16; u++) \
      vb[u] = B[(size_t)((K0) + bkq + u)*512 + bn + bnl]; \
  } while(0)

  GS_LOAD(0);
  for (int it = 0; it < 8; it++){
    #pragma unroll
    for (int hh = 0; hh < 2; hh++){
      short8 ah_, al_, bh_, bl_;
      #pragma unroll
      for (int jj = 0; jj < 8; jj++){
        float v = va[hh*8+jj];
        unsigned short hu = f2u(v);
        ah_[jj] = (short)hu; al_[jj] = (short)f2u(v - b2f_raw(hu));
        v = vb[hh*8+jj];
        hu = f2u(v);
        bh_[jj] = (short)hu; bl_[jj] = (short)f2u(v - b2f_raw(hu));
      }
      int aoff = am*64  + ((((akw>>3) + hh) ^ (am  & 7)) << 3);
      *(short8*)(sAh + aoff) = ah_;
      *(short8*)(sAl + aoff) = al_;
      int boff = bnl*64 + ((((bkq>>3) + hh) ^ (bnl & 7)) << 3);
      *(short8*)(sBh + boff) = bh_;
      *(short8*)(sBl + boff) = bl_;
    }
    __syncthreads();
    if (it < 7) GS_LOAD((it+1)*64);              // prefetch overlaps MFMA below
    #pragma unroll
    for (int ks = 0; ks < 2; ks++){
      int gc = ks*4 + q;
      int ar = w*16 + l16;
      int ao = ar*64 + ((gc ^ (ar & 7)) << 3);
      short8 afh = *(const short8*)(sAh + ao);
      short8 afl = *(const short8*)(sAl + ao);
      #pragma unroll
      for (int nf = 0; nf < 4; nf++){
        int br = nf*16 + l16;
        int bo = br*64 + ((gc ^ (br & 7)) << 3);
        short8 bfh = *(const short8*)(sBh + bo);
        short8 bfl = *(const short8*)(sBl + bo);
        acc[nf] = __builtin_amdgcn_mfma_f32_16x16x32_bf16(afh, bfh, acc[nf], 0, 0, 0);
        acc[nf] = __builtin_amdgcn_mfma_f32_16x16x32_bf16(afh, bfl, acc[nf], 0, 0, 0);
        acc[nf] = __builtin_amdgcn_mfma_f32_16x16x32_bf16(afl, bfh, acc[nf], 0, 0, 0);
      }
    }
    __syncthreads();
  }
  #undef GS_LOAD

  int m0 = bm + w*16 + q*4;
  #pragma unroll
  for (int nf = 0; nf < 4; nf++){
    int n = bn + nf*16 + l16;
    size_t base = (size_t)n*1536 + (size_t)z*512 + m0;
    #pragma unroll
    for (int e = 0; e < 4; e++)
      split_store(acc[nf][e], &Th[base+e], &Tl[base+e]);
  }
}

// ======================= CSR build =======================
__device__ inline void scan_body(const int* __restrict__ counts, int* __restrict__ off,
                                 int* __restrict__ cur, int n, int* __restrict__ sh){
  int t = threadIdx.x;
  int chunk = (n + 1023) >> 10;
  int b = t * chunk; int e = b + chunk; if (e > n) e = n;
  int s = 0;
  for (int i = b; i < e; i++) s += counts[i];
  sh[t] = s; __syncthreads();
  for (int o = 1; o < 1024; o <<= 1){
    int v = (t >= o) ? sh[t-o] : 0;
    __syncthreads();
    sh[t] += v;
    __syncthreads();
  }
  int run = (t > 0) ? sh[t-1] : 0;
  for (int i = b; i < e; i++){ int c = counts[i]; off[i] = run; cur[i] = run; run += c; }
  if (t == 1023) off[n] = sh[1023];
}
__global__ __launch_bounds__(1024) void k_scan(const int* __restrict__ counts,
    int* __restrict__ off, int* __restrict__ cur, int n){
  __shared__ int sh[1024];
  scan_body(counts, off, cur, n, sh);
}
__global__ void k_fill1(const int* __restrict__ src0, const int* __restrict__ tgt0,
                        int* __restrict__ cur, int* __restrict__ esrc, int E, int nn){
  int i = blockIdx.x*blockDim.x + threadIdx.x;
  if (i >= E + nn) return;
  int s, tg;
  if (i < E){ s = src0[i]; tg = tgt0[i]; } else { s = i - E; tg = s; }
  int pos = atomicAdd(&cur[tg], 1);
  esrc[pos] = s;
}
__global__ void k_fill2(const int* __restrict__ src0, const int* __restrict__ tgt0,
                        const int* __restrict__ map, int* __restrict__ cur,
                        int* __restrict__ esrc, int E, int nn){
  int i = blockIdx.x*blockDim.x + threadIdx.x;
  if (i >= E + nn) return;
  int s, tg;
  if (i < E){
    s = map[src0[i]]; tg = map[tgt0[i]];
    if (s < 0 || tg < 0) return;
  } else { s = i - E; tg = s; }
  int pos = atomicAdd(&cur[tg], 1);
  esrc[pos] = s;
}

// ======================= layer 1: aggregate raw x (3 features) =======================
__global__ __launch_bounds__(64) void k_agg1(
    const float* __restrict__ x, const int* __restrict__ off, const int* __restrict__ esrc,
    const float* __restrict__ was, const float* __restrict__ wad,
    float* __restrict__ aggx){          // [n*9], idx h*3+f
  int n = blockIdx.x, t = threadIdx.x;  // 64 threads = 1 wave
  __shared__ float xs[MAXDEG][3];
  __shared__ float al[MAXDEG*3];
  __shared__ float mh[3], dh[3];
  int s0 = off[n]; int deg = off[n+1] - s0; if (deg > MAXDEG) deg = MAXDEG;
  float ad0, ad1, ad2;
  {
    float x0 = x[n*3], x1 = x[n*3+1], x2 = x[n*3+2];
    ad0 = x0*wad[0] + x1*wad[1] + x2*wad[2];
    ad1 = x0*wad[3] + x1*wad[4] + x2*wad[5];
    ad2 = x0*wad[6] + x1*wad[7] + x2*wad[8];
  }
  for (int e = t; e < deg; e += 64){
    int s = esrc[s0 + e];
    float x0 = x[s*3], x1 = x[s*3+1], x2 = x[s*3+2];
    xs[e][0] = x0; xs[e][1] = x1; xs[e][2] = x2;
    float v0 = x0*was[0] + x1*was[1] + x2*was[2] + ad0;
    float v1 = x0*was[3] + x1*was[4] + x2*was[5] + ad1;
    float v2 = x0*was[6] + x1*was[7] + x2*was[8] + ad2;
    al[e*3+0] = v0 > 0.f ? v0 : 0.2f*v0;
    al[e*3+1] = v1 > 0.f ? v1 : 0.2f*v1;
    al[e*3+2] = v2 > 0.f ? v2 : 0.2f*v2;
  }
  __syncthreads();
  if (t < 3){
    float m = -INFINITY;
    for (int e = 0; e < deg; e++) m = fmaxf(m, al[e*3+t]);
    float d = 0.f;
    for (int e = 0; e < deg; e++) d += expf(al[e*3+t] - m);
    mh[t] = m; dh[t] = 1.f / fmaxf(d, 1e-16f);
  }
  __syncthreads();
  float acc[9] = {0,0,0,0,0,0,0,0,0};
  for (int e = t; e < deg; e += 64){
    #pragma unroll
    for (int h = 0; h < 3; h++){
      float a = expf(al[e*3+h] - mh[h]) * dh[h];
      acc[h*3+0] += a * xs[e][0];
      acc[h*3+1] += a * xs[e][1];
      acc[h*3+2] += a * xs[e][2];
    }
  }
  #pragma unroll
  for (int q = 0; q < 9; q++){
    float v = wred64(acc[q]);
    if (t == 0) aggx[(size_t)n*9 + q] = v;
  }
}

// h1[n,j] = relu(cvec[j] + sum_q aggx[n,q]*M1[q,j]) -> bf16 ; 32 nodes/block, fused BN partials
__global__ __launch_bounds__(256) void k_h1(const float* __restrict__ aggx,
    const float* __restrict__ M1p, const float* __restrict__ cvp1, bf16* __restrict__ hout,
    float* __restrict__ bnacc1){
  __shared__ float sM[9*512];
  __shared__ float sC[512];
  __shared__ float sA[32*9];
  int t = threadIdx.x; int n0 = blockIdx.x*32;
  for (int i = t; i < 9*512; i += 256)
    sM[i] = M1p[i] + M1p[4608 + i] + M1p[2*4608 + i] + M1p[3*4608 + i];
  for (int i = t; i < 512; i += 256){
    float s = 0.f;
    #pragma unroll
    for (int kc = 0; kc < 8; kc++) s += cvp1[kc*512 + i];
    sC[i] = s;
  }
  for (int i = t; i < 288; i += 256) sA[i] = aggx[(size_t)n0*9 + i];
  __syncthreads();
  float c0v = sC[t], c1v = sC[t+256];
  float ls0=0.f, lq0=0.f, ls1=0.f, lq1=0.f;
  #pragma unroll 4
  for (int i = 0; i < 32; i++){
    float a0 = c0v, a1 = c1v;
    #pragma unroll
    for (int q = 0; q < 9; q++){
      float av = sA[i*9+q];
      a0 += av * sM[q*512 + t];
      a1 += av * sM[q*512 + t + 256];
    }
    a0 = fmaxf(a0, 0.f); a1 = fmaxf(a1, 0.f);
    hout[(size_t)(n0+i)*512 + t]       = __float2bfloat16(a0);
    hout[(size_t)(n0+i)*512 + t + 256] = __float2bfloat16(a1);
    ls0 += a0; lq0 += a0*a0; ls1 += a1; lq1 += a1*a1;
  }
  atomicAdd(&bnacc1[t],           ls0);
  atomicAdd(&bnacc1[t+256],       ls1);
  atomicAdd(&bnacc1[512 + t],     lq0);
  atomicAdd(&bnacc1[512 + t+256], lq1);
}

// ======================= score (inline BN + inline ||p||) =======================
__global__ __launch_bounds__(256) void k_score(
    const bf16* __restrict__ h, const float* __restrict__ bnacc, int M,
    const float* __restrict__ g_, const float* __restrict__ be,
    const float* __restrict__ p, float* __restrict__ score){
  int r = blockIdx.x, t = threadIdx.x;
  float fM = (float)M;
  float dot = 0.f, pp = 0.f;
  #pragma unroll
  for (int k = 0; k < 2; k++){
    int c = t + k*256;
    float mean, inv; bn_from_acc(bnacc, c, fM, mean, inv);
    float v = (__bfloat162float(h[(size_t)r*EMB + c]) - mean) * inv * g_[c] + be[c];
    float pc = p[c];
    dot += v * pc;
    pp += pc * pc;
  }
  dot = wred64(dot); pp = wred64(pp);
  __shared__ float red[4], redp[4];
  int lane = t & 63, wv = t >> 6;
  if (lane == 0){ red[wv] = dot; redp[wv] = pp; }
  __syncthreads();
  if (t == 0){
    float d = red[0]+red[1]+red[2]+red[3];
    float pn = sqrtf(redp[0]+redp[1]+redp[2]+redp[3]);
    score[r] = tanhf(d / pn);
  }
}

// ======================= top-k =======================
__global__ __launch_bounds__(512) void k_topk_sort(
    const float* __restrict__ score, int* __restrict__ map,
    int* __restrict__ topi, float* __restrict__ tops, int n_per, int K){
  int g = blockIdx.x, t = threadIdx.x;     // 512 threads, 1 elem each
  __shared__ float sk[512];
  __shared__ int si[512];
  if (t < n_per){ sk[t] = score[g*n_per + t]; si[t] = t; }
  else { sk[t] = -INFINITY; si[t] = 0x7fffffff; }
  __syncthreads();
  for (int k = 2; k <= 512; k <<= 1){
    for (int j = k >> 1; j > 0; j >>= 1){
      int l = t ^ j;
      if (l > t){
        float ki = sk[t], kl = sk[l]; int ii = si[t], il = si[l];
        bool before_l = (kl > ki) || (kl == ki && il < ii);
        bool up = ((t & k) == 0);
        if (up == before_l){ sk[t]=kl; sk[l]=ki; si[t]=il; si[l]=ii; }
      }
      __syncthreads();
    }
  }
  if (t < K){
    if (map) map[g*n_per + si[t]] = g*K + t;
    topi[g*K + t] = si[t];
    tops[g*K + t] = sk[t];
  }
}

// gather + inline BN + scale -> bf16; fused layer-2 attention dots; fused count2 tail
__global__ __launch_bounds__(256) void k_gather_c2(
    const bf16* __restrict__ h, const float* __restrict__ bnacc, int M,
    const float* __restrict__ gm, const float* __restrict__ be,
    const int* __restrict__ topi, const float* __restrict__ tops,
    bf16* __restrict__ xn, int n_per, int K,
    const float* __restrict__ was2, const float* __restrict__ wad2,
    float* __restrict__ aso, float* __restrict__ ado,
    const int* __restrict__ src0, const int* __restrict__ tgt0,
    const int* __restrict__ map, int* __restrict__ cnt2, int nblk_g){
  int row = blockIdx.x, t = threadIdx.x;
  if (row >= nblk_g){                      // count2 tail
    int i = (row - nblk_g)*256 + t;
    if (i < E_EDGES){
      int s = map[src0[i]], tg = map[tgt0[i]];
      if (s >= 0 && tg >= 0) atomicAdd(&cnt2[tg], 1);
    }
    return;
  }
  int gr = row / K, i = row - gr*K;
  int sidx = topi[gr*K + i];
  float s = tops[gr*K + i];
  const bf16* src = h + ((size_t)(gr*n_per + sidx))*EMB;
  bf16* dst = xn + (size_t)row*EMB;
  int c0 = t, c1 = t + 256;
  float fM = (float)M;
  float mean0, inv0, mean1, inv1;
  bn_from_acc(bnacc, c0, fM, mean0, inv0);
  bn_from_acc(bnacc, c1, fM, mean1, inv1);
  float v0 = ((__bfloat162float(src[c0]) - mean0) * inv0 * gm[c0] + be[c0]) * s;
  float v1 = ((__bfloat162float(src[c1]) - mean1) * inv1 * gm[c1] + be[c1]) * s;
  dst[c0] = __float2bfloat16(v0);
  dst[c1] = __float2bfloat16(v1);
  {
    float a[6];
    #pragma unroll
    for (int hh = 0; hh < 3; hh++){
      a[hh]   = v0*was2[hh*512 + c0] + v1*was2[hh*512 + c1];
      a[3+hh] = v0*wad2[hh*512 + c0] + v1*wad2[hh*512 + c1];
    }
    __shared__ float red[6][4];
    int lane = t & 63, wv = t >> 6;
    #pragma unroll
    for (int q = 0; q < 6; q++){ float v = wred64(a[q]); if (lane==0) red[q][wv]=v; }
    __syncthreads();
    if (t < 6){
      float sm = red[t][0]+red[t][1]+red[t][2]+red[t][3];
      if (t < 3) aso[row*3+t] = sm; else ado[row*3+(t-3)] = sm;
    }
  }
}

// ======================= pooling =======================
// blocks [0,64): poolA over xn1 (g x 4 col-chunks, 8-way row split); block 64: scan(cnt2)
__global__ __launch_bounds__(1024) void k_poolA_scan(const bf16* __restrict__ xn,
    float* __restrict__ cat, int K,
    const int* __restrict__ cnt2, int* __restrict__ off2, int* __restrict__ cur2){
  __shared__ int shi[1024];
  __shared__ float smax[8][128];
  __shared__ float ssum[8][128];
  int b = blockIdx.x, t = threadIdx.x;
  if (b == 64){ scan_body(cnt2, off2, cur2, NN2, shi); return; }
  int g = b >> 2, cb = b & 3;
  int c = t & 127, rg = t >> 7;
  int col = cb*128 + c;
  const unsigned short* p = (const unsigned short*)xn + (size_t)g*K*EMB + col;
  float mx = -INFINITY, sm = 0.f;
  for (int r = rg; r < K; r += 8){
    float v = b2f_raw(p[(size_t)r*EMB]);
    mx = fmaxf(mx, v); sm += v;
  }
  smax[rg][c] = mx; ssum[rg][c] = sm;
  __syncthreads();
  if (rg == 0){
    #pragma unroll
    for (int u = 1; u < 8; u++){ mx = fmaxf(mx, smax[u][c]); sm += ssum[u][c]; }
    cat[g*1024 + col] = mx;
    cat[g*1024 + 512 + col] = sm / (float)K;
  }
}
// layer-2: fused gather + inline BN + scale + max/mean pool directly from Cc
__global__ __launch_bounds__(1024) void k_poolB(const bf16* __restrict__ h,
    const float* __restrict__ bnacc, int M,
    const float* __restrict__ gm, const float* __restrict__ be,
    const int* __restrict__ topi, const float* __restrict__ tops,
    float* __restrict__ cat, int n_per, int K){
  __shared__ int sti[256];
  __shared__ float sts[256];
  __shared__ float smax[8][128];
  __shared__ float ssum[8][128];
  int b = blockIdx.x, t = threadIdx.x;
  int g = b >> 2, cb = b & 3;
  for (int r = t; r < K; r += 1024){ sti[r] = topi[g*K + r]; sts[r] = tops[g*K + r]; }
  __syncthreads();
  int c = t & 127, rg = t >> 7;
  int col = cb*128 + c;
  float fM = (float)M;
  float mean, inv; bn_from_acc(bnacc, col, fM, mean, inv);
  float gg = gm[col], bb = be[col];
  const unsigned short* hp = (const unsigned short*)h;
  float mx = -INFINITY, sm = 0.f;
  for (int r = rg; r < K; r += 8){
    float v = (b2f_raw(hp[(size_t)(g*n_per + sti[r])*EMB + col]) - mean) * inv * gg + bb;
    v *= sts[r];
    mx = fmaxf(mx, v); sm += v;
  }
  smax[rg][c] = mx; ssum[rg][c] = sm;
  __syncthreads();
  if (rg == 0){
    #pragma unroll
    for (int u = 1; u < 8; u++){ mx = fmaxf(mx, smax[u][c]); sm += ssum[u][c]; }
    cat[g*1024 + col] = mx;
    cat[g*1024 + 512 + col] = sm / (float)K;
  }
}

// ======================= layer 2 aggregation (bf16 xn input) =======================
__global__ __launch_bounds__(256) void k_agg2(
    const bf16* __restrict__ xn, const float* __restrict__ aso, const float* __restrict__ ado,
    const int* __restrict__ off, const int* __restrict__ esrc,
    bf16* __restrict__ oh){
  int n = blockIdx.x, t = threadIdx.x;
  __shared__ int srcs[MAXDEG];
  __shared__ float al[MAXDEG*3];
  __shared__ float mh[3], dh[3];
  int s0 = off[n]; int deg = off[n+1] - s0; if (deg > MAXDEG) deg = MAXDEG;
  for (int e = t; e < deg; e += 256) srcs[e] = esrc[s0 + e];
  __syncthreads();
  float ad0 = ado[n*3+0], ad1 = ado[n*3+1], ad2 = ado[n*3+2];
  for (int e = t; e < deg; e += 256){
    int s = srcs[e];
    float v0 = aso[s*3+0] + ad0, v1 = aso[s*3+1] + ad1, v2 = aso[s*3+2] + ad2;
    al[e*3+0] = v0 > 0.f ? v0 : 0.2f*v0;
    al[e*3+1] = v1 > 0.f ? v1 : 0.2f*v1;
    al[e*3+2] = v2 > 0.f ? v2 : 0.2f*v2;
  }
  __syncthreads();
  if (t < 3){
    float m = -INFINITY;
    for (int e = 0; e < deg; e++) m = fmaxf(m, al[e*3+t]);
    float d = 0.f;
    for (int e = 0; e < deg; e++) d += expf(al[e*3+t] - m);
    mh[t] = m; dh[t] = 1.f / fmaxf(d, 1e-16f);
  }
  __syncthreads();
  for (int e = t; e < deg; e += 256){
    al[e*3+0] = expf(al[e*3+0]-mh[0])*dh[0];
    al[e*3+1] = expf(al[e*3+1]-mh[1])*dh[1];
    al[e*3+2] = expf(al[e*3+2]-mh[2])*dh[2];
  }
  __syncthreads();
  float acc[2][3] = {};
  for (int e = 0; e < deg; e++){
    int s = srcs[e];
    float a0 = al[e*3], a1 = al[e*3+1], a2 = al[e*3+2];
    #pragma unroll
    for (int k = 0; k < 2; k++){
      float v = __bfloat162float(xn[(size_t)s*512 + t + k*256]);
      acc[k][0] += a0*v; acc[k][1] += a1*v; acc[k][2] += a2*v;
    }
  }
  #pragma unroll
  for (int k = 0; k < 2; k++){
    int c = t + k*256;
    #pragma unroll
    for (int h = 0; h < 3; h++)
      oh[(size_t)n*1536 + h*512 + c] = __float2bfloat16(acc[k][h]);
  }
}

// ======================= bf16-A x split-bf16-B MFMA GEMM =======================
__global__ __launch_bounds__(256, 2) void k_gemm_mfma(
    const bf16* __restrict__ Ah,
    const bf16* __restrict__ Bh, const bf16* __restrict__ Bl,   // [N][K] row-major
    const float* __restrict__ bias, bf16* __restrict__ C,
    float* __restrict__ bnacc,
    int M, int N, int K, int Mtiles){
  __shared__ __align__(16) unsigned short lds[2][16384];   // 64 KB total
  int t = threadIdx.x, w = t >> 6, lane = t & 63;
  int q = lane >> 4, l16 = lane & 15;
  int bmi = (int)blockIdx.x % Mtiles, bni = (int)blockIdx.x / Mtiles;
  int bm = bmi * 128, bn = bni * 64;

  int lr = lane >> 3, lc = lane & 7;
  int kg = ((lc ^ lr) & 7) * 8;          // swizzled global k element offset
  int ro = w*8 + lr;
  int m0 = bm + ro, m1 = bm + 32 + ro, m2 = bm + 64 + ro, m3 = bm + 96 + ro;
  if (m0 >= M) m0 = M-1;  if (m1 >= M) m1 = M-1;
  if (m2 >= M) m2 = M-1;  if (m3 >= M) m3 = M-1;
  int n0 = bn + ro, n1 = bn + 32 + ro;
  const bf16* ptr[8];
  ptr[0] = Ah + (size_t)m0*K + kg;
  ptr[1] = Ah + (size_t)m1*K + kg;
  ptr[2] = Ah + (size_t)m2*K + kg;
  ptr[3] = Ah + (size_t)m3*K + kg;
  ptr[4] = Bh + (size_t)n0*K + kg;
  ptr[5] = Bh + (size_t)n1*K + kg;
  ptr[6] = Bl + (size_t)n0*K + kg;
  ptr[7] = Bl + (size_t)n1*K + kg;
  const int dof[8] = {0, 2048, 4096, 6144, 8192, 10240, 12288, 14336};

  int wm = (w >> 1) * 64, wn = (w & 1) * 32;
  f32x4 acc[4][2];
  #pragma unroll
  for (int i = 0; i < 4; i++)
    #pragma unroll
    for (int j = 0; j < 2; j++)
      acc[i][j] = (f32x4){0.f, 0.f, 0.f, 0.f};

  #pragma unroll
  for (int u = 0; u < 8; u++){
    gld16(ptr[u], &lds[0][dof[u] + w*512]);
    ptr[u] += 64;
  }

  int nit = K >> 6;
  for (int it = 0; it < nit; it++){
    __syncthreads();
    int cur = it & 1;
    if (it + 1 < nit){
      int nxt = cur ^ 1;
      #pragma unroll
      for (int u = 0; u < 8; u++){
        gld16(ptr[u], &lds[nxt][dof[u] + w*512]);
        ptr[u] += 64;
      }
    }
    const unsigned short* L = lds[cur];
    #pragma unroll
    for (int ks = 0; ks < 2; ks++){
      short8 ah[4], bh2[2], bl2[2];
      int gc = ks*4 + q;
      #pragma unroll
      for (int i = 0; i < 4; i++){
        int r = wm + i*16 + l16;
        ah[i] = *(const short8*)(L + r*64 + ((gc ^ (r & 7)) << 3));
      }
      #pragma unroll
      for (int j = 0; j < 2; j++){
        int r = wn + j*16 + l16;
        int so = ((gc ^ (r & 7)) << 3);
        bh2[j] = *(const short8*)(L + 8192  + r*64 + so);
        bl2[j] = *(const short8*)(L + 12288 + r*64 + so);
      }
      #pragma unroll
      for (int i = 0; i < 4; i++)
        #pragma unroll
        for (int j = 0; j < 2; j++){
          acc[i][j] = __builtin_amdgcn_mfma_f32_16x16x32_bf16(ah[i], bh2[j], acc[i][j], 0, 0, 0);
          acc[i][j] = __builtin_amdgcn_mfma_f32_16x16x32_bf16(ah[i], bl2[j], acc[i][j], 0, 0, 0);
        }
    }
  }

  // epilogue: relu + bf16 store + per-column BN partials
  __syncthreads();                       // LDS now free for reduction scratch
  float* cs = (float*)&lds[0][0];        // [2][64] col sums | [2][64] col sqs
  float* cq = cs + 128;
  int slot = w >> 1;
  #pragma unroll
  for (int j = 0; j < 2; j++){
    int c_local = wn + j*16 + l16;
    int c = bn + c_local;
    float bv = 0.f;
    if (bias){
      #pragma unroll
      for (int kc = 0; kc < 8; kc++) bv += bias[kc*512 + c];
    }
    float ls = 0.f, lq = 0.f;
    #pragma unroll
    for (int i = 0; i < 4; i++){
      int rb = bm + wm + i*16 + q*4;
      #pragma unroll
      for (int e = 0; e < 4; e++){
        int r = rb + e;
        if (r < M){
          float v = fmaxf(acc[i][j][e] + bv, 0.f);
          C[(size_t)r*N + c] = __float2bfloat16(v);
          ls += v; lq += v*v;
        }
      }
    }
    ls += __shfl_xor(ls, 16); ls += __shfl_xor(ls, 32);
    lq += __shfl_xor(lq, 16); lq += __shfl_xor(lq, 32);
    if (q == 0){ cs[slot*64 + c_local] = ls; cq[slot*64 + c_local] = lq; }
  }
  __syncthreads();
  if (t < 64){
    atomicAdd(&bnacc[bn + t],        cs[t] + cs[64 + t]);
    atomicAdd(&bnacc[512 + bn + t],  cq[t] + cq[64 + t]);
  }
}

// ======================= head =======================
__global__ __launch_bounds__(256) void k_head1(const float* __restrict__ c1,
    const float* __restrict__ c2, const float* __restrict__ Wl1,
    const float* __restrict__ bl1, float* __restrict__ t1){
  int g = blockIdx.y;
  int jj = threadIdx.x & 63, kc = threadIdx.x >> 6;
  int j = blockIdx.x*64 + jj;
  float acc = 0.f;
  for (int k = kc*256; k < kc*256 + 256; k++){
    float xg = c1[g*1024 + k] + c2[g*1024 + k];
    acc += xg * Wl1[(size_t)k*512 + j];
  }
  __shared__ float red[4][64];
  red[kc][jj] = acc;
  __syncthreads();
  if (kc == 0){
    float v = red[0][jj]+red[1][jj]+red[2][jj]+red[3][jj] + bl1[j];
    t1[g*512 + j] = fmaxf(v, 0.f);
  }
}
__global__ __launch_bounds__(256) void k_head2(const float* __restrict__ t1,
    const float* __restrict__ Wl2, const float* __restrict__ bl2, float* __restrict__ out){
  int g = blockIdx.y;
  int jj = threadIdx.x & 63, kc = threadIdx.x >> 6;
  int j = blockIdx.x*64 + jj;
  float acc = 0.f;
  for (int k = kc*128; k < kc*128 + 128; k++)
    acc += t1[g*512 + k] * Wl2[(size_t)k*256 + j];
  __shared__ float red[4][64];
  red[kc][jj] = acc;
  __syncthreads();
  if (kc == 0)
    out[g*256 + j] = red[0][jj]+red[1][jj]+red[2][jj]+red[3][jj] + bl2[j];
}

extern "C" void kernel_launch(void* const* d_in, const int* in_sizes, int n_in,
                              void* d_out, int out_size, void* d_ws, size_t ws_size,
                              hipStream_t stream){
  const float* x   = (const float*)d_in[0];
  const int*   ei  = (const int*)d_in[1];
  const float* W1  = (const float*)d_in[2];
  const float* as1 = (const float*)d_in[3];
  const float* ad1 = (const float*)d_in[4];
  const float* bc1 = (const float*)d_in[5];
  const float* Wh1 = (const float*)d_in[6];
  const float* bh1 = (const float*)d_in[7];
  const float* g1  = (const float*)d_in[8];
  const float* be1 = (const float*)d_in[9];
  const float* p1  = (const float*)d_in[10];
  const float* W2  = (const float*)d_in[11];
  const float* as2 = (const float*)d_in[12];
  const float* ad2 = (const float*)d_in[13];
  const float* bc2 = (const float*)d_in[14];
  const float* Wh2 = (const float*)d_in[15];
  const float* bh2 = (const float*)d_in[16];
  const float* g2  = (const float*)d_in[17];
  const float* be2 = (const float*)d_in[18];
  const float* p2  = (const float*)d_in[19];
  const float* Wl1 = (const float*)d_in[20];
  const float* bl1 = (const float*)d_in[21];
  const float* Wl2 = (const float*)d_in[22];
  const float* bl2 = (const float*)d_in[23];
  float* out = (float*)d_out;

  const int* src0 = ei;
  const int* tgt0 = ei + E_EDGES;

  // ---- workspace layout ----
  bf16* Cc     = (bf16*)d_ws;                        // 8192*512 bf16 (h1 -> h2)
  bf16* xn1    = Cc + (size_t)NN1*EMB;               // 6560*512 bf16
  bf16* xn2    = xn1 + (size_t)NN2*EMB;              // (unused hole)
  float* aggx1 = (float*)(xn2 + (size_t)NG*KP2*EMB + 8); // 8192*9
  float* M1    = aggx1 + (size_t)NN1*9;              // (unused)
  float* was2  = M1 + 9*EMB;                         // 3*512
  float* wad2  = was2 + 3*EMB;
  float* cvec1 = wad2 + 3*EMB;                       // (unused)
  float* cvec2 = cvec1 + EMB;
  float* was1  = cvec2 + EMB;                        // 16
  float* wad1  = was1 + 16;
  float* bnpsum= wad1 + 16;                          // reused: bnacc1 (layer-1 BN sums)
  float* bnpsq = bnpsum + (size_t)BNCH*EMB;          // reused: M1p + cvp
  float* stats = bnpsq + (size_t)BNCH*EMB;           // (unused)
  float* bnacc = stats + 1024;                       // 1024 (layer-2 direct sums)
  float* pn    = bnacc + 1024;                       // (unused)
  float* score = pn + 16;                            // 8192
  float* cat1  = score + NN1;                        // 16*1024
  float* cat2  = cat1 + NG*1024;
  float* t1h   = cat2 + NG*1024;                     // 16*512
  float* pmax  = t1h + NG*EMB;                       // (unused hole)
  float* psum  = pmax + NG*16*EMB;                   // (unused hole)
  float* aso2  = psum + NG*16*EMB;                   // 6560*3
  float* ado2  = aso2 + NN2*3;
  float* tops  = ado2 + NN2*3;                       // 16*410
  bf16* aggx2h = (bf16*)(tops + NG*KP1);             // 6560*1536 (bf16, hi only)
  bf16* M2Th   = aggx2h + (size_t)NN2*F1;            // 512*1536
  bf16* M2Tl   = M2Th + (size_t)EMB*F1;
  int* map     = (int*)(M2Tl + (size_t)EMB*F1);      // 8192
  int* cnt1    = map + NN1;
  int* off1    = cnt1 + NN1;                         // 8200
  int* cur1    = off1 + NN1 + 8;
  int* esrc1   = cur1 + NN1;                         // 139264
  int* cnt2    = esrc1 + (E_EDGES + NN1);
  int* off2    = cnt2 + NN2;                         // 6568
  int* cur2    = off2 + NN2 + 8;
  int* esrc2   = cur2 + NN2;                         // 137700 (pad)
  int* topi    = esrc2 + 137700;                     // 16*410

  float* bnacc1 = bnpsum;                            // layer-1 BN accumulator (1024 floats)
  float* M1p    = bnpsq;                             // 4*4608 floats (M1 K-chunk partials)
  float* cvp    = bnpsq + 4*4608;                    // 16*512 floats (cvec K-chunk partials)
  float* cvp2   = cvp + 8*512;                       // which=1 region (layer-2 bias partials)

  // ---- precompute (fused, latency-parallel) ----
  k_pre<<<202,256,0,stream>>>(W1,as1,ad1,Wh1,bc1,bh1, W2,as2,ad2,Wh2,bc2,bh2,
                              was1,wad1,M1p,cvp,was2,wad2,
                              cnt1,cnt2,map,bnacc,bnacc1);
  // gemm_s (192 blocks) + count1 (512 blocks)
  k_gemm_s_c1<<<704,256,0,stream>>>(W2,Wh2,M2Th,M2Tl,tgt0,cnt1);

  // ---- layer 1 ----
  k_scan<<<1,1024,0,stream>>>(cnt1,off1,cur1,NN1);
  k_fill1<<<(E_EDGES+NN1+255)/256,256,0,stream>>>(src0,tgt0,cur1,esrc1,E_EDGES,NN1);
  k_agg1<<<NN1,64,0,stream>>>(x,off1,esrc1,was1,wad1,aggx1);
  k_h1<<<NN1/32,256,0,stream>>>(aggx1,M1p,cvp,Cc,bnacc1);
  k_score<<<NN1,256,0,stream>>>(Cc,bnacc1,NN1,g1,be1,p1,score);
  k_topk_sort<<<NG,512,0,stream>>>(score,map,topi,tops,NP1,KP1);
  // gather (6560 blocks) + count2 (512 blocks)
  k_gather_c2<<<NG*KP1+512,256,0,stream>>>(Cc,bnacc1,NN1,g1,be1,topi,tops,xn1,NP1,KP1,
      was2,wad2,aso2,ado2, src0,tgt0,map,cnt2,NG*KP1);
  // poolA (64 blocks) + scan2 (block 64)
  k_poolA_scan<<<65,1024,0,stream>>>(xn1,cat1,KP1, cnt2,off2,cur2);

  // ---- layer 2 ----
  k_fill2<<<(E_EDGES+NN2+255)/256,256,0,stream>>>(src0,tgt0,map,cur2,esrc2,E_EDGES,NN2);
  k_agg2<<<NN2,256,0,stream>>>(xn1,aso2,ado2,off2,esrc2,aggx2h);
  k_gemm_mfma<<<52*8,256,0,stream>>>(aggx2h,M2Th,M2Tl,cvp2,Cc,bnacc,NN2,EMB,F1,52);
  k_score<<<NN2,256,0,stream>>>(Cc,bnacc,NN2,g2,be2,p2,score);
  k_topk_sort<<<NG,512,0,stream>>>(score,(int*)nullptr,topi,tops,KP1,KP2);
  k_poolB<<<64,1024,0,stream>>>(Cc,bnacc,NN2,g2,be2,topi,tops,cat2,KP1,KP2);

  // ---- head ----
  k_head1<<<dim3(8,NG),256,0,stream>>>(cat1,cat2,Wl1,bl1,t1h);
  k_head2<<<dim3(4,NG),256,0,stream>>>(t1h,Wl2,bl2,out);
}